// Round 15
// baseline (591.575 us; speedup 1.0000x reference)
//
#include <hip/hip_runtime.h>

#define NB 2
#define NH 20
#define TT 2048
#define DD 1280
#define DHH 64
#define SP 2048
#define SS 4096
#define MM (NB*TT)

typedef __attribute__((ext_vector_type(8))) short bf16x8;
typedef __attribute__((ext_vector_type(4))) float f32x4;
typedef unsigned short u16;
typedef unsigned int u32;

__device__ __forceinline__ f32x4 mfma16(bf16x8 a, bf16x8 b, f32x4 c) {
  return __builtin_amdgcn_mfma_f32_16x16x32_bf16(a, b, c, 0, 0, 0);
}

// round-to-nearest-even f32 -> bf16 bits
__device__ __forceinline__ u16 f2bf(float f) {
  u32 x = __builtin_bit_cast(u32, f);
  x += 0x7fffu + ((x >> 16) & 1u);
  return (u16)(x >> 16);
}
__device__ __forceinline__ float bf2f(u16 u) {
  u32 x = ((u32)u) << 16;
  return __builtin_bit_cast(float, x);
}

__device__ __forceinline__ float fexp2(float x) {
#if __has_builtin(__builtin_amdgcn_exp2f)
  return __builtin_amdgcn_exp2f(x);
#else
  return exp2f(x);
#endif
}

__device__ __forceinline__ u32 cvtpk(float lo, float hi) {
  u32 r;
  asm("v_cvt_pk_bf16_f32 %0, %1, %2" : "=v"(r) : "v"(lo), "v"(hi));
  return r;
}

__device__ __forceinline__ float vmax3(float a, float b, float c) {
  float d;
  asm("v_max3_f32 %0, %1, %2, %3" : "=v"(d) : "v"(a), "v"(b), "v"(c));
  return d;
}
// max of 16 f32 (4x f32x4) via max3 tree
__device__ __forceinline__ float max16(const f32x4* st) {
  float m0 = vmax3(st[0][0], st[0][1], st[0][2]);
  float m1 = vmax3(st[0][3], st[1][0], st[1][1]);
  float m2 = vmax3(st[1][2], st[1][3], st[2][0]);
  float m3 = vmax3(st[2][1], st[2][2], st[2][3]);
  float m4 = vmax3(st[3][0], st[3][1], st[3][2]);
  float m5 = vmax3(m0, m1, st[3][3]);
  float m6 = vmax3(m2, m3, m4);
  return fmaxf(m5, m6);
}

#define VMCNT0() asm volatile("s_waitcnt vmcnt(0)" ::: "memory")
#define BAR() __builtin_amdgcn_s_barrier()

__device__ __forceinline__ void gload16(const u16* src, char* ldst) {
  __builtin_amdgcn_global_load_lds(
      (const __attribute__((address_space(1))) u32*)src,
      (__attribute__((address_space(3))) u32*)ldst, 16, 0, 0);
}

// chunk cc (k cc*8..cc*8+7) of `row`, 128B rows
__device__ __forceinline__ bf16x8 frag_swz(const char* lds, int row, int cc) {
  return *(const bf16x8*)(lds + row * 128 + ((cc ^ (row & 7)) << 4));
}
// 64B rows (BK=32 tiles)
__device__ __forceinline__ bf16x8 frag32(const char* lds, int row, int cc) {
  return *(const bf16x8*)(lds + row * 64 + ((cc ^ (row & 3)) << 4));
}

// ---------------- x -> bf16 hi/lo split ----------------
__global__ void splitx(const float* __restrict__ x, u16* __restrict__ xh,
                       u16* __restrict__ xl) {
  int i = blockIdx.x * 256 + threadIdx.x;
  float4 v = ((const float4*)x)[i];
  ushort4 hi, lo;
  hi.x = f2bf(v.x); lo.x = f2bf(v.x - bf2f(hi.x));
  hi.y = f2bf(v.y); lo.y = f2bf(v.y - bf2f(hi.y));
  hi.z = f2bf(v.z); lo.z = f2bf(v.z - bf2f(hi.z));
  hi.w = f2bf(v.w); lo.w = f2bf(v.w - bf2f(hi.w));
  ((ushort4*)xh)[i] = hi;
  ((ushort4*)xl)[i] = lo;
}

// ---------------- weight transpose + split ----------------
__global__ void transw(const float* __restrict__ wq, const float* __restrict__ wk,
                       const float* __restrict__ wv, const float* __restrict__ wo,
                       u16* __restrict__ wqkvh, u16* __restrict__ wqkvl,
                       u16* __restrict__ wot) {
  __shared__ float tile[64][65];
  int mat = blockIdx.z;
  const float* src = mat == 0 ? wq : mat == 1 ? wk : mat == 2 ? wv : wo;
  int k0 = blockIdx.x * 64, n0 = blockIdx.y * 64;
  int tid = threadIdx.x;
#pragma unroll
  for (int rep = 0; rep < 16; ++rep) {
    int id = rep * 256 + tid;
    int kl = id >> 6, nl = id & 63;
    tile[nl][kl] = src[(k0 + kl) * DD + n0 + nl];
  }
  __syncthreads();
#pragma unroll
  for (int rep = 0; rep < 16; ++rep) {
    int id = rep * 256 + tid;
    int nl = id >> 6, kl = id & 63;
    float v = tile[nl][kl];
    u16 hi = f2bf(v);
    if (mat < 3) {
      int idx = (mat * DD + n0 + nl) * DD + k0 + kl;
      wqkvh[idx] = hi;
      wqkvl[idx] = f2bf(v - bf2f(hi));
    } else {
      wot[(n0 + nl) * DD + k0 + kl] = hi;
    }
  }
}

// ---------------- past K: f32 copy + hi/lo bf16 ----------------
__global__ void pastk(const float* __restrict__ pK, float* __restrict__ dK,
                      u16* __restrict__ Kh, u16* __restrict__ Kl) {
  int i = blockIdx.x * 256 + threadIdx.x;
  int e = i * 4;
  int dh = e & 63;
  int s = (e >> 6) & (SP - 1);
  int bh = e >> 17;
  float4 v = *(const float4*)(pK + e);
  int o = (bh * SS + s) * DHH + dh;
  *(float4*)(dK + o) = v;
  ushort4 hi, lo;
  hi.x = f2bf(v.x); lo.x = f2bf(v.x - bf2f(hi.x));
  hi.y = f2bf(v.y); lo.y = f2bf(v.y - bf2f(hi.y));
  hi.z = f2bf(v.z); lo.z = f2bf(v.z - bf2f(hi.z));
  hi.w = f2bf(v.w); lo.w = f2bf(v.w - bf2f(hi.w));
  *(ushort4*)(Kh + o) = hi;
  *(ushort4*)(Kl + o) = lo;
}

// ---------------- past V: f32 copy + bf16 transpose into Vt[bh][dh][s] ------
__global__ void pastv(const float* __restrict__ pV, float* __restrict__ dV,
                      u16* __restrict__ Vt) {
  __shared__ u16 tile[64][72];
  int bi = blockIdx.x;
  int bh = bi >> 5, st = bi & 31;
  int s0 = st * 64;
  int tid = threadIdx.x;
  const float* src = pV + (bh * SP + s0) * DHH;
  float* dst = dV + (bh * SS + s0) * DHH;
#pragma unroll
  for (int rep = 0; rep < 16; ++rep) {
    int id = rep * 256 + tid;
    int sl = id >> 6, dh = id & 63;
    float v = src[sl * DHH + dh];
    dst[sl * DHH + dh] = v;
    tile[dh][sl] = f2bf(v);
  }
  __syncthreads();
  u16* vdst = Vt + (bh * DHH) * SS + s0;
#pragma unroll
  for (int rep = 0; rep < 4; ++rep) {
    int id = rep * 256 + tid;
    int dh = id >> 4, s4 = (id & 15) * 4;
    ushort4 vv;
    vv.x = tile[dh][s4];     vv.y = tile[dh][s4 + 1];
    vv.z = tile[dh][s4 + 2]; vv.w = tile[dh][s4 + 3];
    *(ushort4*)(vdst + dh * SS + s4) = vv;
  }
}

// ---------------- fused QKV split GEMM: [4096,1280] x [1280,3840] ----------
// BK=32, double-buffered LDS, counted-wait pipeline.
// Q,K columns: 3-pass split bf16. V columns: 1-pass.
__launch_bounds__(256, 2)
__global__ void gemm_qkv(const u16* __restrict__ xh, const u16* __restrict__ xl,
                         const u16* __restrict__ wh, const u16* __restrict__ wl,
                         u16* __restrict__ Qh, u16* __restrict__ Ql,
                         u16* __restrict__ Kh, u16* __restrict__ Kl,
                         u16* __restrict__ Vt,
                         float* __restrict__ dK, float* __restrict__ dV) {
  __shared__ __align__(16) char sm[65536];  // 2 bufs x {Ah,Al,Bh,Bl} x 8KB
  int tid = threadIdx.x, lane = tid & 63, w = tid >> 6;
  int wm = w >> 1, wn = w & 1;
  int r15 = lane & 15, grp = lane >> 4;
  int mBase = blockIdx.x * 128;
  int by = blockIdx.y;
  int nGlob = by * 128;
  const bool split = (by < 20);
  f32x4 acc[4][4] = {};
  int id0 = tid, id1 = 256 + tid;
  int r0 = id0 >> 2, c0 = id0 & 3;
  int r1 = id1 >> 2, c1 = id1 & 3;
  int so0 = r0 * DD + (c0 ^ (r0 & 3)) * 8;
  int so1 = r1 * DD + (c1 ^ (r1 & 3)) * 8;
  const u16* aH = xh + mBase * DD;
  const u16* aL = xl + mBase * DD;
  const u16* bH = wh + nGlob * DD;
  const u16* bL = wl + nGlob * DD;
  int do0 = id0 * 16, do1 = id1 * 16;

  auto stage = [&](int buf, int k0) {
    char* b = sm + buf * 32768;
    gload16(aH + k0 + so0, b + do0);
    gload16(aH + k0 + so1, b + do1);
    gload16(bH + k0 + so0, b + 16384 + do0);
    gload16(bH + k0 + so1, b + 16384 + do1);
    if (split) {
      gload16(aL + k0 + so0, b + 8192 + do0);
      gload16(aL + k0 + so1, b + 8192 + do1);
      gload16(bL + k0 + so0, b + 24576 + do0);
      gload16(bL + k0 + so1, b + 24576 + do1);
    }
  };
  auto compute = [&](int buf) {
    const char* b = sm + buf * 32768;
    bf16x8 fah[4], fal[4], fbh[4], fbl[4];
#pragma unroll
    for (int i = 0; i < 4; ++i) {
      fah[i] = frag32(b, wm * 64 + i * 16 + r15, grp);
      fbh[i] = frag32(b + 16384, wn * 64 + i * 16 + r15, grp);
      if (split) {
        fal[i] = frag32(b + 8192, wm * 64 + i * 16 + r15, grp);
        fbl[i] = frag32(b + 24576, wn * 64 + i * 16 + r15, grp);
      }
    }
    __builtin_amdgcn_s_setprio(1);
    if (split) {
#pragma unroll
      for (int i = 0; i < 4; ++i)
#pragma unroll
        for (int j = 0; j < 4; ++j) {
          acc[i][j] = mfma16(fah[i], fbh[j], acc[i][j]);
          acc[i][j] = mfma16(fah[i], fbl[j], acc[i][j]);
          acc[i][j] = mfma16(fal[i], fbh[j], acc[i][j]);
        }
    } else {
#pragma unroll
      for (int i = 0; i < 4; ++i)
#pragma unroll
        for (int j = 0; j < 4; ++j)
          acc[i][j] = mfma16(fah[i], fbh[j], acc[i][j]);
    }
    __builtin_amdgcn_s_setprio(0);
  };

  stage(0, 0);
  VMCNT0(); BAR();
#pragma unroll 2
  for (int step = 0; step < 39; ++step) {
    stage((step + 1) & 1, (step + 1) * 32);
    compute(step & 1);
    VMCNT0(); BAR();
  }
  compute(1);  // step 39

  int proj = by / 10;
  int nb = (by % 10) * 128 + wn * 64;
#pragma unroll
  for (int i = 0; i < 4; ++i)
#pragma unroll
    for (int j = 0; j < 4; ++j)
#pragma unroll
      for (int r = 0; r < 4; ++r) {
        int m = mBase + wm * 64 + i * 16 + grp * 4 + r;
        int n = nb + j * 16 + r15;
        float v = acc[i][j][r];
        int b = m >> 11, t = m & 2047;
        int h = n >> 6, dh = n & 63;
        int bhh = b * NH + h;
        if (proj == 0) {
          float q = v * 0.180336880111f;  // 1/8 * log2(e): exp2-domain softmax
          u16 hi = f2bf(q);
          int idx = (bhh * TT + t) * DHH + dh;
          Qh[idx] = hi;
          Ql[idx] = f2bf(q - bf2f(hi));
        } else if (proj == 1) {
          int idx = (bhh * SS + SP + t) * DHH + dh;
          dK[idx] = v;
          u16 hi = f2bf(v);
          Kh[idx] = hi;
          Kl[idx] = f2bf(v - bf2f(hi));
        } else {
          int idx = (bhh * SS + SP + t) * DHH + dh;
          dV[idx] = v;
          Vt[(bhh * DHH + dh) * SS + SP + t] = f2bf(v);
        }
      }
}

// ---------------- flash attention ----------------
// R13-green structure, single change: V is NOT staged through LDS. The per-bh
// KV set (~1.5MB) is L2-resident under XCD clustering, so PV reads V frags
// directly from global Vt[bh][dh][s] (identical values frag_swz(Vs,..) gave).
// Drops Vs (8KB LDS -> 4 blocks/CU), 2 gloads/thread/chunk, 8 LDS reads/
// wave-chunk; V loads now inside if(act).
__launch_bounds__(256, 4)
__global__ void attn(const u16* __restrict__ Qh, const u16* __restrict__ Ql,
                     const u16* __restrict__ Kh, const u16* __restrict__ Kl,
                     const u16* __restrict__ Vt, u16* __restrict__ ao) {
  __shared__ __align__(16) char Ks[8192];
  __shared__ __align__(16) char Kls[8192];
  __shared__ __align__(16) u16 Pw[4][2][16][72];
  __shared__ __align__(16) float bc[4][16];
  int d = blockIdx.x;
  // XCD swizzle: cluster each bh's 16 q-blocks on one XCD (5 bh per XCD)
  int xcd = d & 7, sl = d >> 3;
  int bh = xcd * 5 + (sl >> 4);
  int q0 = (sl & 15) * 128;
  int tid = threadIdx.x, lane = tid & 63, w = tid >> 6;
  int r15 = lane & 15, grp = lane >> 4;
  int qbase = q0 + w * 32;
  bf16x8 fqh[2][2], fql[2][2];
#pragma unroll
  for (int qt = 0; qt < 2; ++qt) {
    int qrow = qbase + qt * 16 + r15;
    const u16* qb = Qh + (bh * TT + qrow) * DHH + grp * 8;
    const u16* qbl = Ql + (bh * TT + qrow) * DHH + grp * 8;
    fqh[qt][0] = *(const bf16x8*)qb;   fqh[qt][1] = *(const bf16x8*)(qb + 32);
    fql[qt][0] = *(const bf16x8*)qbl;  fql[qt][1] = *(const bf16x8*)(qbl + 32);
  }
  float mrun[2] = {-1e30f, -1e30f};
  float lrun[2] = {0.f, 0.f};
  f32x4 oacc[2][4] = {};
  int id0 = tid, id1 = 256 + tid;
  int r0 = id0 >> 3, c0 = id0 & 7;
  int r1 = id1 >> 3, c1 = id1 & 7;
  const u16* kh0 = Kh + bh * SS * DHH + r0 * DHH + (c0 ^ (r0 & 7)) * 8;
  const u16* kh1 = Kh + bh * SS * DHH + r1 * DHH + (c1 ^ (r1 & 7)) * 8;
  const u16* kl0 = Kl + bh * SS * DHH + r0 * DHH + (c0 ^ (r0 & 7)) * 8;
  const u16* kl1 = Kl + bh * SS * DHH + r1 * DHH + (c1 ^ (r1 & 7)) * 8;
  // direct V access: this lane's row within each dd-block of V^T
  const u16* vlane = Vt + bh * DHH * SS + r15 * SS + grp * 8;
  char* dK0 = Ks + id0 * 16;  char* dK1 = Ks + id1 * 16;
  char* dL0 = Kls + id0 * 16; char* dL1 = Kls + id1 * 16;

  for (int it = 0; it < SS / 64; ++it) {
    gload16(kh0, dK0); gload16(kh1, dK1);
    gload16(kl0, dL0); gload16(kl1, dL1);
    kh0 += 64 * DHH; kh1 += 64 * DHH;
    kl0 += 64 * DHH; kl1 += 64 * DHH;
    __syncthreads();
    // ---- hi-only QK^T ----
    f32x4 st[2][4];
    __builtin_amdgcn_s_setprio(1);
#pragma unroll
    for (int kt = 0; kt < 4; ++kt) {
      bf16x8 k0f = frag_swz(Ks, kt * 16 + r15, grp);
      bf16x8 k1f = frag_swz(Ks, kt * 16 + r15, 4 + grp);
#pragma unroll
      for (int qt = 0; qt < 2; ++qt) {
        f32x4 a = {0.f, 0.f, 0.f, 0.f};
        a = mfma16(k0f, fqh[qt][0], a);
        a = mfma16(k1f, fqh[qt][1], a);
        st[qt][kt] = a;
      }
    }
    __builtin_amdgcn_s_setprio(0);
    // chunk max of hi scores per q-col
    float cm[2];
#pragma unroll
    for (int qt = 0; qt < 2; ++qt) {
      float c = max16(st[qt]);
      c = fmaxf(c, __shfl_xor(c, 16));
      c = fmaxf(c, __shfl_xor(c, 32));
      cm[qt] = c;
    }
    bool act = (!__all(cm[0] <= mrun[0] - 88.f)) |
               (!__all(cm[1] <= mrun[1] - 88.f));
    if (act) {
      // ---- lo refine: re-read K-hi + K-lo frags from LDS ----
      __builtin_amdgcn_s_setprio(1);
#pragma unroll
      for (int kt = 0; kt < 4; ++kt) {
        bf16x8 k0f = frag_swz(Ks, kt * 16 + r15, grp);
        bf16x8 k1f = frag_swz(Ks, kt * 16 + r15, 4 + grp);
        bf16x8 l0f = frag_swz(Kls, kt * 16 + r15, grp);
        bf16x8 l1f = frag_swz(Kls, kt * 16 + r15, 4 + grp);
#pragma unroll
        for (int qt = 0; qt < 2; ++qt) {
          st[qt][kt] = mfma16(l0f, fqh[qt][0], st[qt][kt]);
          st[qt][kt] = mfma16(k0f, fql[qt][0], st[qt][kt]);
          st[qt][kt] = mfma16(l1f, fqh[qt][1], st[qt][kt]);
          st[qt][kt] = mfma16(k1f, fql[qt][1], st[qt][kt]);
        }
      }
      __builtin_amdgcn_s_setprio(0);
      // ---- softmax + pack per q-tile ----
#pragma unroll
      for (int qt = 0; qt < 2; ++qt) {
        if (!__all(cm[qt] <= mrun[qt] + 8.f)) {  // defer-max rescale
          float mnew = fmaxf(mrun[qt], cm[qt]);
          float sc = fexp2(mrun[qt] - mnew);
          lrun[qt] *= sc;
          mrun[qt] = mnew;
          if (grp == 0) bc[w][r15] = sc;
          f32x4 scv = *(const f32x4*)&bc[w][grp * 4];
#pragma unroll
          for (int dd = 0; dd < 4; ++dd) {
            oacc[qt][dd][0] *= scv[0]; oacc[qt][dd][1] *= scv[1];
            oacc[qt][dd][2] *= scv[2]; oacc[qt][dd][3] *= scv[3];
          }
        }
        float m = mrun[qt];
        float ps = 0.f;
#pragma unroll
        for (int kt = 0; kt < 4; ++kt)
#pragma unroll
          for (int r = 0; r < 4; ++r) {
            float p = fexp2(st[qt][kt][r] - m);
            st[qt][kt][r] = p;
            ps += p;
          }
        ps += __shfl_xor(ps, 16);
        ps += __shfl_xor(ps, 32);
        lrun[qt] += ps;
#pragma unroll
        for (int kt = 0; kt < 4; ++kt) {
          u32 w0 = cvtpk(st[qt][kt][0], st[qt][kt][1]);
          u32 w1 = cvtpk(st[qt][kt][2], st[qt][kt][3]);
          uint2 pk = {w0, w1};
          *(uint2*)&Pw[w][qt][r15][kt * 16 + grp * 4] = pk;
        }
      }
      // ---- PV: V frags direct from global (L2-hit), shared across q-tiles --
      bf16x8 pa[2][2];
#pragma unroll
      for (int qt = 0; qt < 2; ++qt) {
        pa[qt][0] = *(const bf16x8*)&Pw[w][qt][r15][grp * 8];
        pa[qt][1] = *(const bf16x8*)&Pw[w][qt][r15][32 + grp * 8];
      }
      const u16* vp = vlane + it * 64;
      __builtin_amdgcn_s_setprio(1);
#pragma unroll
      for (int dd = 0; dd < 4; ++dd) {
        bf16x8 vf0 = *(const bf16x8*)(vp + dd * 16 * SS);
        bf16x8 vf1 = *(const bf16x8*)(vp + dd * 16 * SS + 32);
#pragma unroll
        for (int qt = 0; qt < 2; ++qt) {
          oacc[qt][dd] = mfma16(pa[qt][0], vf0, oacc[qt][dd]);
          oacc[qt][dd] = mfma16(pa[qt][1], vf1, oacc[qt][dd]);
        }
      }
      __builtin_amdgcn_s_setprio(0);
    }
    __syncthreads();
  }
  int b = bh / NH, h = bh % NH;
#pragma unroll
  for (int qt = 0; qt < 2; ++qt) {
    float inv = 1.0f / lrun[qt];
    if (grp == 0) bc[w][r15] = inv;
    f32x4 li = *(const f32x4*)&bc[w][grp * 4];
#pragma unroll
    for (int dd = 0; dd < 4; ++dd)
#pragma unroll
      for (int r = 0; r < 4; ++r) {
        int q = qbase + qt * 16 + grp * 4 + r;
        int col = h * DHH + dd * 16 + r15;
        ao[(b * TT + q) * DD + col] = f2bf(oacc[qt][dd][r] * li[r]);
      }
  }
}

// ---------------- out = values @ W_o (single bf16) ----------------
// BK=32 double-buffered counted-wait pipeline (clone of gemm_qkv split=false).
__launch_bounds__(256, 3)
__global__ void gemm_out(const u16* __restrict__ ao, const u16* __restrict__ wot,
                         float* __restrict__ out) {
  __shared__ __align__(16) char sm[32768];  // 2 bufs x {A 8KB, B 8KB}
  int tid = threadIdx.x, lane = tid & 63, w = tid >> 6;
  int wm = w >> 1, wn = w & 1;
  int r15 = lane & 15, grp = lane >> 4;
  int mBase = blockIdx.x * 128, nBase = blockIdx.y * 128;
  f32x4 acc[4][4] = {};
  int id0 = tid, id1 = 256 + tid;
  int r0 = id0 >> 2, c0 = id0 & 3;
  int r1 = id1 >> 2, c1 = id1 & 3;
  int so0 = r0 * DD + (c0 ^ (r0 & 3)) * 8;
  int so1 = r1 * DD + (c1 ^ (r1 & 3)) * 8;
  const u16* aP = ao + mBase * DD;
  const u16* bP = wot + nBase * DD;
  int do0 = id0 * 16, do1 = id1 * 16;

  auto stage = [&](int buf, int k0) {
    char* b = sm + buf * 16384;
    gload16(aP + k0 + so0, b + do0);
    gload16(aP + k0 + so1, b + do1);
    gload16(bP + k0 + so0, b + 8192 + do0);
    gload16(bP + k0 + so1, b + 8192 + do1);
  };
  auto compute = [&](int buf) {
    const char* b = sm + buf * 16384;
    bf16x8 fa[4], fb[4];
#pragma unroll
    for (int i = 0; i < 4; ++i) {
      fa[i] = frag32(b, wm * 64 + i * 16 + r15, grp);
      fb[i] = frag32(b + 8192, wn * 64 + i * 16 + r15, grp);
    }
    __builtin_amdgcn_s_setprio(1);
#pragma unroll
    for (int i = 0; i < 4; ++i)
#pragma unroll
      for (int j = 0; j < 4; ++j)
        acc[i][j] = mfma16(fa[i], fb[j], acc[i][j]);
    __builtin_amdgcn_s_setprio(0);
  };

  stage(0, 0);
  VMCNT0(); BAR();
#pragma unroll 2
  for (int step = 0; step < 39; ++step) {
    stage((step + 1) & 1, (step + 1) * 32);
    compute(step & 1);
    VMCNT0(); BAR();
  }
  compute(1);  // step 39

#pragma unroll
  for (int i = 0; i < 4; ++i)
#pragma unroll
    for (int j = 0; j < 4; ++j)
#pragma unroll
      for (int r = 0; r < 4; ++r) {
        int m = mBase + wm * 64 + i * 16 + grp * 4 + r;
        int n = nBase + wn * 64 + j * 16 + r15;
        out[m * DD + n] = acc[i][j][r];
      }
}

extern "C" void kernel_launch(void* const* d_in, const int* in_sizes, int n_in,
                              void* d_out, int out_size, void* d_ws, size_t ws_size,
                              hipStream_t stream) {
  const float* x  = (const float*)d_in[0];
  const float* pK = (const float*)d_in[1];
  const float* pV = (const float*)d_in[2];
  const float* wq = (const float*)d_in[3];
  const float* wk = (const float*)d_in[4];
  const float* wv = (const float*)d_in[5];
  const float* wo = (const float*)d_in[6];

  float* out = (float*)d_out;            // [B,T,D]
  float* dK  = out + NB * TT * DD;       // [B,H,S,DH]
  float* dV  = dK + NB * NH * SS * DHH;  // [B,H,S,DH]

  u16* xh    = (u16*)d_ws;               // [4096][1280]
  u16* xl    = xh + MM * DD;
  u16* wqkvh = xl + MM * DD;             // [3840][1280] transposed weights
  u16* wqkvl = wqkvh + 3 * DD * DD;
  u16* wot   = wqkvl + 3 * DD * DD;      // [1280][1280]
  u16* Qh    = wot + DD * DD;            // [B,H,T,DH] (pre-scaled, exp2 domain)
  u16* Ql    = Qh + MM * DD;
  u16* Kh    = Ql + MM * DD;             // [B,H,S,DH]
  u16* Kl    = Kh + NB * NH * SS * DHH;
  u16* Vt    = Kl + NB * NH * SS * DHH;  // [B,H,DH,S]
  u16* ao    = xh;                       // alias: x dead after gemm_qkv

  splitx<<<dim3(MM * DD / 4 / 256), 256, 0, stream>>>(x, xh, xl);
  transw<<<dim3(20, 20, 4), 256, 0, stream>>>(wq, wk, wv, wo, wqkvh, wqkvl, wot);
  pastk<<<dim3(NB * NH * SP * DHH / 4 / 256), 256, 0, stream>>>(pK, dK, Kh, Kl);
  pastv<<<dim3(NB * NH * (SP / 64)), 256, 0, stream>>>(pV, dV, Vt);
  gemm_qkv<<<dim3(32, 30), 256, 0, stream>>>(xh, xl, wqkvh, wqkvl,
                                             Qh, Ql, Kh, Kl, Vt, dK, dV);
  attn<<<dim3(NB * NH * (TT / 128)), 256, 0, stream>>>(Qh, Ql, Kh, Kl, Vt, ao);
  gemm_out<<<dim3(32, 10), 256, 0, stream>>>(ao, wot, out);
}

// Round 16
// 377.989 us; speedup vs baseline: 1.5651x; 1.5651x over previous
//
#include <hip/hip_runtime.h>

#define NB 2
#define NH 20
#define TT 2048
#define DD 1280
#define DHH 64
#define SP 2048
#define SS 4096
#define MM (NB*TT)

typedef __attribute__((ext_vector_type(8))) short bf16x8;
typedef __attribute__((ext_vector_type(4))) float f32x4;
typedef unsigned short u16;
typedef unsigned int u32;

__device__ __forceinline__ f32x4 mfma16(bf16x8 a, bf16x8 b, f32x4 c) {
  return __builtin_amdgcn_mfma_f32_16x16x32_bf16(a, b, c, 0, 0, 0);
}

// round-to-nearest-even f32 -> bf16 bits
__device__ __forceinline__ u16 f2bf(float f) {
  u32 x = __builtin_bit_cast(u32, f);
  x += 0x7fffu + ((x >> 16) & 1u);
  return (u16)(x >> 16);
}
__device__ __forceinline__ float bf2f(u16 u) {
  u32 x = ((u32)u) << 16;
  return __builtin_bit_cast(float, x);
}

__device__ __forceinline__ float fexp2(float x) {
#if __has_builtin(__builtin_amdgcn_exp2f)
  return __builtin_amdgcn_exp2f(x);
#else
  return exp2f(x);
#endif
}

__device__ __forceinline__ u32 cvtpk(float lo, float hi) {
  u32 r;
  asm("v_cvt_pk_bf16_f32 %0, %1, %2" : "=v"(r) : "v"(lo), "v"(hi));
  return r;
}

__device__ __forceinline__ float vmax3(float a, float b, float c) {
  float d;
  asm("v_max3_f32 %0, %1, %2, %3" : "=v"(d) : "v"(a), "v"(b), "v"(c));
  return d;
}
// max of 16 f32 (4x f32x4) via max3 tree
__device__ __forceinline__ float max16(const f32x4* st) {
  float m0 = vmax3(st[0][0], st[0][1], st[0][2]);
  float m1 = vmax3(st[0][3], st[1][0], st[1][1]);
  float m2 = vmax3(st[1][2], st[1][3], st[2][0]);
  float m3 = vmax3(st[2][1], st[2][2], st[2][3]);
  float m4 = vmax3(st[3][0], st[3][1], st[3][2]);
  float m5 = vmax3(m0, m1, st[3][3]);
  float m6 = vmax3(m2, m3, m4);
  return fmaxf(m5, m6);
}

#define VMCNT0() asm volatile("s_waitcnt vmcnt(0)" ::: "memory")
#define BAR() __builtin_amdgcn_s_barrier()

__device__ __forceinline__ void gload16(const u16* src, char* ldst) {
  __builtin_amdgcn_global_load_lds(
      (const __attribute__((address_space(1))) u32*)src,
      (__attribute__((address_space(3))) u32*)ldst, 16, 0, 0);
}

// chunk cc (k cc*8..cc*8+7) of `row`, 128B rows
__device__ __forceinline__ bf16x8 frag_swz(const char* lds, int row, int cc) {
  return *(const bf16x8*)(lds + row * 128 + ((cc ^ (row & 7)) << 4));
}
// 64B rows (BK=32 tiles)
__device__ __forceinline__ bf16x8 frag32(const char* lds, int row, int cc) {
  return *(const bf16x8*)(lds + row * 64 + ((cc ^ (row & 3)) << 4));
}

// ---------------- x -> bf16 hi/lo split ----------------
__global__ void splitx(const float* __restrict__ x, u16* __restrict__ xh,
                       u16* __restrict__ xl) {
  int i = blockIdx.x * 256 + threadIdx.x;
  float4 v = ((const float4*)x)[i];
  ushort4 hi, lo;
  hi.x = f2bf(v.x); lo.x = f2bf(v.x - bf2f(hi.x));
  hi.y = f2bf(v.y); lo.y = f2bf(v.y - bf2f(hi.y));
  hi.z = f2bf(v.z); lo.z = f2bf(v.z - bf2f(hi.z));
  hi.w = f2bf(v.w); lo.w = f2bf(v.w - bf2f(hi.w));
  ((ushort4*)xh)[i] = hi;
  ((ushort4*)xl)[i] = lo;
}

// ---------------- weight transpose + split ----------------
__global__ void transw(const float* __restrict__ wq, const float* __restrict__ wk,
                       const float* __restrict__ wv, const float* __restrict__ wo,
                       u16* __restrict__ wqkvh, u16* __restrict__ wqkvl,
                       u16* __restrict__ wot) {
  __shared__ float tile[64][65];
  int mat = blockIdx.z;
  const float* src = mat == 0 ? wq : mat == 1 ? wk : mat == 2 ? wv : wo;
  int k0 = blockIdx.x * 64, n0 = blockIdx.y * 64;
  int tid = threadIdx.x;
#pragma unroll
  for (int rep = 0; rep < 16; ++rep) {
    int id = rep * 256 + tid;
    int kl = id >> 6, nl = id & 63;
    tile[nl][kl] = src[(k0 + kl) * DD + n0 + nl];
  }
  __syncthreads();
#pragma unroll
  for (int rep = 0; rep < 16; ++rep) {
    int id = rep * 256 + tid;
    int nl = id >> 6, kl = id & 63;
    float v = tile[nl][kl];
    u16 hi = f2bf(v);
    if (mat < 3) {
      int idx = (mat * DD + n0 + nl) * DD + k0 + kl;
      wqkvh[idx] = hi;
      wqkvl[idx] = f2bf(v - bf2f(hi));
    } else {
      wot[(n0 + nl) * DD + k0 + kl] = hi;
    }
  }
}

// ---------------- past K: f32 copy + hi/lo bf16 ----------------
__global__ void pastk(const float* __restrict__ pK, float* __restrict__ dK,
                      u16* __restrict__ Kh, u16* __restrict__ Kl) {
  int i = blockIdx.x * 256 + threadIdx.x;
  int e = i * 4;
  int dh = e & 63;
  int s = (e >> 6) & (SP - 1);
  int bh = e >> 17;
  float4 v = *(const float4*)(pK + e);
  int o = (bh * SS + s) * DHH + dh;
  *(float4*)(dK + o) = v;
  ushort4 hi, lo;
  hi.x = f2bf(v.x); lo.x = f2bf(v.x - bf2f(hi.x));
  hi.y = f2bf(v.y); lo.y = f2bf(v.y - bf2f(hi.y));
  hi.z = f2bf(v.z); lo.z = f2bf(v.z - bf2f(hi.z));
  hi.w = f2bf(v.w); lo.w = f2bf(v.w - bf2f(hi.w));
  *(ushort4*)(Kh + o) = hi;
  *(ushort4*)(Kl + o) = lo;
}

// ---------------- past V: f32 copy + bf16 transpose into Vt[bh][dh][s] ------
__global__ void pastv(const float* __restrict__ pV, float* __restrict__ dV,
                      u16* __restrict__ Vt) {
  __shared__ u16 tile[64][72];
  int bi = blockIdx.x;
  int bh = bi >> 5, st = bi & 31;
  int s0 = st * 64;
  int tid = threadIdx.x;
  const float* src = pV + (bh * SP + s0) * DHH;
  float* dst = dV + (bh * SS + s0) * DHH;
#pragma unroll
  for (int rep = 0; rep < 16; ++rep) {
    int id = rep * 256 + tid;
    int sl = id >> 6, dh = id & 63;
    float v = src[sl * DHH + dh];
    dst[sl * DHH + dh] = v;
    tile[dh][sl] = f2bf(v);
  }
  __syncthreads();
  u16* vdst = Vt + (bh * DHH) * SS + s0;
#pragma unroll
  for (int rep = 0; rep < 4; ++rep) {
    int id = rep * 256 + tid;
    int dh = id >> 4, s4 = (id & 15) * 4;
    ushort4 vv;
    vv.x = tile[dh][s4];     vv.y = tile[dh][s4 + 1];
    vv.z = tile[dh][s4 + 2]; vv.w = tile[dh][s4 + 3];
    *(ushort4*)(vdst + dh * SS + s4) = vv;
  }
}

// ---------------- fused QKV split GEMM: [4096,1280] x [1280,3840] ----------
// BK=32, double-buffered LDS, counted-wait pipeline.
// Q,K columns: 3-pass split bf16. V columns: 1-pass.
__launch_bounds__(256, 2)
__global__ void gemm_qkv(const u16* __restrict__ xh, const u16* __restrict__ xl,
                         const u16* __restrict__ wh, const u16* __restrict__ wl,
                         u16* __restrict__ Qh, u16* __restrict__ Ql,
                         u16* __restrict__ Kh, u16* __restrict__ Kl,
                         u16* __restrict__ Vt,
                         float* __restrict__ dK, float* __restrict__ dV) {
  __shared__ __align__(16) char sm[65536];  // 2 bufs x {Ah,Al,Bh,Bl} x 8KB
  int tid = threadIdx.x, lane = tid & 63, w = tid >> 6;
  int wm = w >> 1, wn = w & 1;
  int r15 = lane & 15, grp = lane >> 4;
  int mBase = blockIdx.x * 128;
  int by = blockIdx.y;
  int nGlob = by * 128;
  const bool split = (by < 20);
  f32x4 acc[4][4] = {};
  int id0 = tid, id1 = 256 + tid;
  int r0 = id0 >> 2, c0 = id0 & 3;
  int r1 = id1 >> 2, c1 = id1 & 3;
  int so0 = r0 * DD + (c0 ^ (r0 & 3)) * 8;
  int so1 = r1 * DD + (c1 ^ (r1 & 3)) * 8;
  const u16* aH = xh + mBase * DD;
  const u16* aL = xl + mBase * DD;
  const u16* bH = wh + nGlob * DD;
  const u16* bL = wl + nGlob * DD;
  int do0 = id0 * 16, do1 = id1 * 16;

  auto stage = [&](int buf, int k0) {
    char* b = sm + buf * 32768;
    gload16(aH + k0 + so0, b + do0);
    gload16(aH + k0 + so1, b + do1);
    gload16(bH + k0 + so0, b + 16384 + do0);
    gload16(bH + k0 + so1, b + 16384 + do1);
    if (split) {
      gload16(aL + k0 + so0, b + 8192 + do0);
      gload16(aL + k0 + so1, b + 8192 + do1);
      gload16(bL + k0 + so0, b + 24576 + do0);
      gload16(bL + k0 + so1, b + 24576 + do1);
    }
  };
  auto compute = [&](int buf) {
    const char* b = sm + buf * 32768;
    bf16x8 fah[4], fal[4], fbh[4], fbl[4];
#pragma unroll
    for (int i = 0; i < 4; ++i) {
      fah[i] = frag32(b, wm * 64 + i * 16 + r15, grp);
      fbh[i] = frag32(b + 16384, wn * 64 + i * 16 + r15, grp);
      if (split) {
        fal[i] = frag32(b + 8192, wm * 64 + i * 16 + r15, grp);
        fbl[i] = frag32(b + 24576, wn * 64 + i * 16 + r15, grp);
      }
    }
    __builtin_amdgcn_s_setprio(1);
    if (split) {
#pragma unroll
      for (int i = 0; i < 4; ++i)
#pragma unroll
        for (int j = 0; j < 4; ++j) {
          acc[i][j] = mfma16(fah[i], fbh[j], acc[i][j]);
          acc[i][j] = mfma16(fah[i], fbl[j], acc[i][j]);
          acc[i][j] = mfma16(fal[i], fbh[j], acc[i][j]);
        }
    } else {
#pragma unroll
      for (int i = 0; i < 4; ++i)
#pragma unroll
        for (int j = 0; j < 4; ++j)
          acc[i][j] = mfma16(fah[i], fbh[j], acc[i][j]);
    }
    __builtin_amdgcn_s_setprio(0);
  };

  stage(0, 0);
  VMCNT0(); BAR();
#pragma unroll 2
  for (int step = 0; step < 39; ++step) {
    stage((step + 1) & 1, (step + 1) * 32);
    compute(step & 1);
    VMCNT0(); BAR();
  }
  compute(1);  // step 39

  int proj = by / 10;
  int nb = (by % 10) * 128 + wn * 64;
#pragma unroll
  for (int i = 0; i < 4; ++i)
#pragma unroll
    for (int j = 0; j < 4; ++j)
#pragma unroll
      for (int r = 0; r < 4; ++r) {
        int m = mBase + wm * 64 + i * 16 + grp * 4 + r;
        int n = nb + j * 16 + r15;
        float v = acc[i][j][r];
        int b = m >> 11, t = m & 2047;
        int h = n >> 6, dh = n & 63;
        int bhh = b * NH + h;
        if (proj == 0) {
          float q = v * 0.180336880111f;  // 1/8 * log2(e): exp2-domain softmax
          u16 hi = f2bf(q);
          int idx = (bhh * TT + t) * DHH + dh;
          Qh[idx] = hi;
          Ql[idx] = f2bf(q - bf2f(hi));
        } else if (proj == 1) {
          int idx = (bhh * SS + SP + t) * DHH + dh;
          dK[idx] = v;
          u16 hi = f2bf(v);
          Kh[idx] = hi;
          Kl[idx] = f2bf(v - bf2f(hi));
        } else {
          int idx = (bhh * SS + SP + t) * DHH + dh;
          dV[idx] = v;
          Vt[(bhh * DHH + dh) * SS + SP + t] = f2bf(v);
        }
      }
}

// ---------------- flash attention (R13-proven, unchanged) ----------------
// 128 q-rows/block (4 waves x 32), S in 64-chunks, XCD-clustered bh.
// Hi-first skip + 3-pass refine; lrun scalar accumulation; bc-LDS broadcasts.
__launch_bounds__(256, 3)
__global__ void attn(const u16* __restrict__ Qh, const u16* __restrict__ Ql,
                     const u16* __restrict__ Kh, const u16* __restrict__ Kl,
                     const u16* __restrict__ Vt, u16* __restrict__ ao) {
  __shared__ __align__(16) char Ks[8192];
  __shared__ __align__(16) char Kls[8192];
  __shared__ __align__(16) char Vs[8192];
  __shared__ __align__(16) u16 Pw[4][2][16][72];
  __shared__ __align__(16) float bc[4][16];
  int d = blockIdx.x;
  // XCD swizzle: cluster each bh's 16 q-blocks on one XCD (5 bh per XCD)
  int xcd = d & 7, sl = d >> 3;
  int bh = xcd * 5 + (sl >> 4);
  int q0 = (sl & 15) * 128;
  int tid = threadIdx.x, lane = tid & 63, w = tid >> 6;
  int r15 = lane & 15, grp = lane >> 4;
  int qbase = q0 + w * 32;
  bf16x8 fqh[2][2], fql[2][2];
#pragma unroll
  for (int qt = 0; qt < 2; ++qt) {
    int qrow = qbase + qt * 16 + r15;
    const u16* qb = Qh + (bh * TT + qrow) * DHH + grp * 8;
    const u16* qbl = Ql + (bh * TT + qrow) * DHH + grp * 8;
    fqh[qt][0] = *(const bf16x8*)qb;   fqh[qt][1] = *(const bf16x8*)(qb + 32);
    fql[qt][0] = *(const bf16x8*)qbl;  fql[qt][1] = *(const bf16x8*)(qbl + 32);
  }
  float mrun[2] = {-1e30f, -1e30f};
  float lrun[2] = {0.f, 0.f};
  f32x4 oacc[2][4] = {};
  int id0 = tid, id1 = 256 + tid;
  int r0 = id0 >> 3, c0 = id0 & 7;
  int r1 = id1 >> 3, c1 = id1 & 7;
  const u16* kh0 = Kh + bh * SS * DHH + r0 * DHH + (c0 ^ (r0 & 7)) * 8;
  const u16* kh1 = Kh + bh * SS * DHH + r1 * DHH + (c1 ^ (r1 & 7)) * 8;
  const u16* kl0 = Kl + bh * SS * DHH + r0 * DHH + (c0 ^ (r0 & 7)) * 8;
  const u16* kl1 = Kl + bh * SS * DHH + r1 * DHH + (c1 ^ (r1 & 7)) * 8;
  const u16* v0 = Vt + bh * DHH * SS + r0 * SS + (c0 ^ (r0 & 7)) * 8;
  const u16* v1 = Vt + bh * DHH * SS + r1 * SS + (c1 ^ (r1 & 7)) * 8;
  char* dK0 = Ks + id0 * 16;  char* dK1 = Ks + id1 * 16;
  char* dL0 = Kls + id0 * 16; char* dL1 = Kls + id1 * 16;
  char* dV0 = Vs + id0 * 16;  char* dV1 = Vs + id1 * 16;

  for (int it = 0; it < SS / 64; ++it) {
    gload16(kh0, dK0); gload16(kh1, dK1);
    gload16(kl0, dL0); gload16(kl1, dL1);
    gload16(v0, dV0);  gload16(v1, dV1);
    kh0 += 64 * DHH; kh1 += 64 * DHH;
    kl0 += 64 * DHH; kl1 += 64 * DHH;
    v0 += 64; v1 += 64;
    __syncthreads();
    // ---- hi-only QK^T ----
    f32x4 st[2][4];
    __builtin_amdgcn_s_setprio(1);
#pragma unroll
    for (int kt = 0; kt < 4; ++kt) {
      bf16x8 k0f = frag_swz(Ks, kt * 16 + r15, grp);
      bf16x8 k1f = frag_swz(Ks, kt * 16 + r15, 4 + grp);
#pragma unroll
      for (int qt = 0; qt < 2; ++qt) {
        f32x4 a = {0.f, 0.f, 0.f, 0.f};
        a = mfma16(k0f, fqh[qt][0], a);
        a = mfma16(k1f, fqh[qt][1], a);
        st[qt][kt] = a;
      }
    }
    __builtin_amdgcn_s_setprio(0);
    // chunk max of hi scores per q-col
    float cm[2];
#pragma unroll
    for (int qt = 0; qt < 2; ++qt) {
      float c = max16(st[qt]);
      c = fmaxf(c, __shfl_xor(c, 16));
      c = fmaxf(c, __shfl_xor(c, 32));
      cm[qt] = c;
    }
    bool act = (!__all(cm[0] <= mrun[0] - 88.f)) |
               (!__all(cm[1] <= mrun[1] - 88.f));
    if (act) {
      // ---- lo refine: re-read K-hi + K-lo frags from LDS ----
      __builtin_amdgcn_s_setprio(1);
#pragma unroll
      for (int kt = 0; kt < 4; ++kt) {
        bf16x8 k0f = frag_swz(Ks, kt * 16 + r15, grp);
        bf16x8 k1f = frag_swz(Ks, kt * 16 + r15, 4 + grp);
        bf16x8 l0f = frag_swz(Kls, kt * 16 + r15, grp);
        bf16x8 l1f = frag_swz(Kls, kt * 16 + r15, 4 + grp);
#pragma unroll
        for (int qt = 0; qt < 2; ++qt) {
          st[qt][kt] = mfma16(l0f, fqh[qt][0], st[qt][kt]);
          st[qt][kt] = mfma16(k0f, fql[qt][0], st[qt][kt]);
          st[qt][kt] = mfma16(l1f, fqh[qt][1], st[qt][kt]);
          st[qt][kt] = mfma16(k1f, fql[qt][1], st[qt][kt]);
        }
      }
      __builtin_amdgcn_s_setprio(0);
      // ---- softmax + pack per q-tile ----
#pragma unroll
      for (int qt = 0; qt < 2; ++qt) {
        if (!__all(cm[qt] <= mrun[qt] + 8.f)) {  // defer-max rescale
          float mnew = fmaxf(mrun[qt], cm[qt]);
          float sc = fexp2(mrun[qt] - mnew);
          lrun[qt] *= sc;
          mrun[qt] = mnew;
          if (grp == 0) bc[w][r15] = sc;
          f32x4 scv = *(const f32x4*)&bc[w][grp * 4];
#pragma unroll
          for (int dd = 0; dd < 4; ++dd) {
            oacc[qt][dd][0] *= scv[0]; oacc[qt][dd][1] *= scv[1];
            oacc[qt][dd][2] *= scv[2]; oacc[qt][dd][3] *= scv[3];
          }
        }
        float m = mrun[qt];
        float ps = 0.f;
#pragma unroll
        for (int kt = 0; kt < 4; ++kt)
#pragma unroll
          for (int r = 0; r < 4; ++r) {
            float p = fexp2(st[qt][kt][r] - m);
            st[qt][kt][r] = p;
            ps += p;
          }
        ps += __shfl_xor(ps, 16);
        ps += __shfl_xor(ps, 32);
        lrun[qt] += ps;
#pragma unroll
        for (int kt = 0; kt < 4; ++kt) {
          u32 w0 = cvtpk(st[qt][kt][0], st[qt][kt][1]);
          u32 w1 = cvtpk(st[qt][kt][2], st[qt][kt][3]);
          uint2 pk = {w0, w1};
          *(uint2*)&Pw[w][qt][r15][kt * 16 + grp * 4] = pk;
        }
      }
      // ---- PV: V frags shared across both q-tiles ----
      bf16x8 pa[2][2];
#pragma unroll
      for (int qt = 0; qt < 2; ++qt) {
        pa[qt][0] = *(const bf16x8*)&Pw[w][qt][r15][grp * 8];
        pa[qt][1] = *(const bf16x8*)&Pw[w][qt][r15][32 + grp * 8];
      }
      __builtin_amdgcn_s_setprio(1);
#pragma unroll
      for (int dd = 0; dd < 4; ++dd) {
        bf16x8 vf0 = frag_swz(Vs, dd * 16 + r15, grp);
        bf16x8 vf1 = frag_swz(Vs, dd * 16 + r15, 4 + grp);
#pragma unroll
        for (int qt = 0; qt < 2; ++qt) {
          oacc[qt][dd] = mfma16(pa[qt][0], vf0, oacc[qt][dd]);
          oacc[qt][dd] = mfma16(pa[qt][1], vf1, oacc[qt][dd]);
        }
      }
      __builtin_amdgcn_s_setprio(0);
    }
    __syncthreads();
  }
  int b = bh / NH, h = bh % NH;
#pragma unroll
  for (int qt = 0; qt < 2; ++qt) {
    float inv = 1.0f / lrun[qt];
    if (grp == 0) bc[w][r15] = inv;
    f32x4 li = *(const f32x4*)&bc[w][grp * 4];
#pragma unroll
    for (int dd = 0; dd < 4; ++dd)
#pragma unroll
      for (int r = 0; r < 4; ++r) {
        int q = qbase + qt * 16 + grp * 4 + r;
        int col = h * DHH + dd * 16 + r15;
        ao[(b * TT + q) * DD + col] = f2bf(oacc[qt][dd][r] * li[r]);
      }
  }
}

// ---------------- out = values @ W_o (single bf16) ----------------
// BK=32 double-buffered counted-wait pipeline (clone of gemm_qkv split=false).
__launch_bounds__(256, 3)
__global__ void gemm_out(const u16* __restrict__ ao, const u16* __restrict__ wot,
                         float* __restrict__ out) {
  __shared__ __align__(16) char sm[32768];  // 2 bufs x {A 8KB, B 8KB}
  int tid = threadIdx.x, lane = tid & 63, w = tid >> 6;
  int wm = w >> 1, wn = w & 1;
  int r15 = lane & 15, grp = lane >> 4;
  int mBase = blockIdx.x * 128, nBase = blockIdx.y * 128;
  f32x4 acc[4][4] = {};
  int id0 = tid, id1 = 256 + tid;
  int r0 = id0 >> 2, c0 = id0 & 3;
  int r1 = id1 >> 2, c1 = id1 & 3;
  int so0 = r0 * DD + (c0 ^ (r0 & 3)) * 8;
  int so1 = r1 * DD + (c1 ^ (r1 & 3)) * 8;
  const u16* aP = ao + mBase * DD;
  const u16* bP = wot + nBase * DD;
  int do0 = id0 * 16, do1 = id1 * 16;

  auto stage = [&](int buf, int k0) {
    char* b = sm + buf * 16384;
    gload16(aP + k0 + so0, b + do0);
    gload16(aP + k0 + so1, b + do1);
    gload16(bP + k0 + so0, b + 8192 + do0);
    gload16(bP + k0 + so1, b + 8192 + do1);
  };
  auto compute = [&](int buf) {
    const char* b = sm + buf * 16384;
    bf16x8 fa[4], fb[4];
#pragma unroll
    for (int i = 0; i < 4; ++i) {
      fa[i] = frag32(b, wm * 64 + i * 16 + r15, grp);
      fb[i] = frag32(b + 8192, wn * 64 + i * 16 + r15, grp);
    }
    __builtin_amdgcn_s_setprio(1);
#pragma unroll
    for (int i = 0; i < 4; ++i)
#pragma unroll
      for (int j = 0; j < 4; ++j)
        acc[i][j] = mfma16(fa[i], fb[j], acc[i][j]);
    __builtin_amdgcn_s_setprio(0);
  };

  stage(0, 0);
  VMCNT0(); BAR();
#pragma unroll 2
  for (int step = 0; step < 39; ++step) {
    stage((step + 1) & 1, (step + 1) * 32);
    compute(step & 1);
    VMCNT0(); BAR();
  }
  compute(1);  // step 39

#pragma unroll
  for (int i = 0; i < 4; ++i)
#pragma unroll
    for (int j = 0; j < 4; ++j)
#pragma unroll
      for (int r = 0; r < 4; ++r) {
        int m = mBase + wm * 64 + i * 16 + grp * 4 + r;
        int n = nBase + wn * 64 + j * 16 + r15;
        out[m * DD + n] = acc[i][j][r];
      }
}

extern "C" void kernel_launch(void* const* d_in, const int* in_sizes, int n_in,
                              void* d_out, int out_size, void* d_ws, size_t ws_size,
                              hipStream_t stream) {
  const float* x  = (const float*)d_in[0];
  const float* pK = (const float*)d_in[1];
  const float* pV = (const float*)d_in[2];
  const float* wq = (const float*)d_in[3];
  const float* wk = (const float*)d_in[4];
  const float* wv = (const float*)d_in[5];
  const float* wo = (const float*)d_in[6];

  float* out = (float*)d_out;            // [B,T,D]
  float* dK  = out + NB * TT * DD;       // [B,H,S,DH]
  float* dV  = dK + NB * NH * SS * DHH;  // [B,H,S,DH]

  u16* xh    = (u16*)d_ws;               // [4096][1280]
  u16* xl    = xh + MM * DD;
  u16* wqkvh = xl + MM * DD;             // [3840][1280] transposed weights
  u16* wqkvl = wqkvh + 3 * DD * DD;
  u16* wot   = wqkvl + 3 * DD * DD;      // [1280][1280]
  u16* Qh    = wot + DD * DD;            // [B,H,T,DH] (pre-scaled, exp2 domain)
  u16* Ql    = Qh + MM * DD;
  u16* Kh    = Ql + MM * DD;             // [B,H,S,DH]
  u16* Kl    = Kh + NB * NH * SS * DHH;
  u16* Vt    = Kl + NB * NH * SS * DHH;  // [B,H,DH,S]
  u16* ao    = xh;                       // alias: x dead after gemm_qkv

  splitx<<<dim3(MM * DD / 4 / 256), 256, 0, stream>>>(x, xh, xl);
  transw<<<dim3(20, 20, 4), 256, 0, stream>>>(wq, wk, wv, wo, wqkvh, wqkvl, wot);
  pastk<<<dim3(NB * NH * SP * DHH / 4 / 256), 256, 0, stream>>>(pK, dK, Kh, Kl);
  pastv<<<dim3(NB * NH * (SP / 64)), 256, 0, stream>>>(pV, dV, Vt);
  gemm_qkv<<<dim3(32, 30), 256, 0, stream>>>(xh, xl, wqkvh, wqkvl,
                                             Qh, Ql, Kh, Kl, Vt, dK, dV);
  attn<<<dim3(NB * NH * (TT / 128)), 256, 0, stream>>>(Qh, Ql, Kh, Kl, Vt, ao);
  gemm_out<<<dim3(32, 10), 256, 0, stream>>>(ao, wot, out);
}

// Round 17
// 369.669 us; speedup vs baseline: 1.6003x; 1.0225x over previous
//
#include <hip/hip_runtime.h>

#define NB 2
#define NH 20
#define TT 2048
#define DD 1280
#define DHH 64
#define SP 2048
#define SS 4096
#define MM (NB*TT)

typedef __attribute__((ext_vector_type(8))) short bf16x8;
typedef __attribute__((ext_vector_type(4))) float f32x4;
typedef unsigned short u16;
typedef unsigned int u32;

__device__ __forceinline__ f32x4 mfma16(bf16x8 a, bf16x8 b, f32x4 c) {
  return __builtin_amdgcn_mfma_f32_16x16x32_bf16(a, b, c, 0, 0, 0);
}

// round-to-nearest-even f32 -> bf16 bits
__device__ __forceinline__ u16 f2bf(float f) {
  u32 x = __builtin_bit_cast(u32, f);
  x += 0x7fffu + ((x >> 16) & 1u);
  return (u16)(x >> 16);
}
__device__ __forceinline__ float bf2f(u16 u) {
  u32 x = ((u32)u) << 16;
  return __builtin_bit_cast(float, x);
}

__device__ __forceinline__ float fexp2(float x) {
#if __has_builtin(__builtin_amdgcn_exp2f)
  return __builtin_amdgcn_exp2f(x);
#else
  return exp2f(x);
#endif
}

__device__ __forceinline__ u32 cvtpk(float lo, float hi) {
  u32 r;
  asm("v_cvt_pk_bf16_f32 %0, %1, %2" : "=v"(r) : "v"(lo), "v"(hi));
  return r;
}

__device__ __forceinline__ float vmax3(float a, float b, float c) {
  float d;
  asm("v_max3_f32 %0, %1, %2, %3" : "=v"(d) : "v"(a), "v"(b), "v"(c));
  return d;
}
// max of 16 f32 (4x f32x4) via max3 tree
__device__ __forceinline__ float max16(const f32x4* st) {
  float m0 = vmax3(st[0][0], st[0][1], st[0][2]);
  float m1 = vmax3(st[0][3], st[1][0], st[1][1]);
  float m2 = vmax3(st[1][2], st[1][3], st[2][0]);
  float m3 = vmax3(st[2][1], st[2][2], st[2][3]);
  float m4 = vmax3(st[3][0], st[3][1], st[3][2]);
  float m5 = vmax3(m0, m1, st[3][3]);
  float m6 = vmax3(m2, m3, m4);
  return fmaxf(m5, m6);
}

#define VMCNT0() asm volatile("s_waitcnt vmcnt(0)" ::: "memory")
#define BAR() __builtin_amdgcn_s_barrier()

__device__ __forceinline__ void gload16(const u16* src, char* ldst) {
  __builtin_amdgcn_global_load_lds(
      (const __attribute__((address_space(1))) u32*)src,
      (__attribute__((address_space(3))) u32*)ldst, 16, 0, 0);
}

// chunk cc (k cc*8..cc*8+7) of `row`, 128B rows
__device__ __forceinline__ bf16x8 frag_swz(const char* lds, int row, int cc) {
  return *(const bf16x8*)(lds + row * 128 + ((cc ^ (row & 7)) << 4));
}
// 64B rows (BK=32 tiles)
__device__ __forceinline__ bf16x8 frag32(const char* lds, int row, int cc) {
  return *(const bf16x8*)(lds + row * 64 + ((cc ^ (row & 3)) << 4));
}

// ---------------- fused prep: splitx | transw | pastk | pastv ----------------
// 4 independent memory-bound stages in one dispatch (block-range dispatch,
// wave-uniform branch). Bodies identical to the proven separate kernels.
#define PREP_SPLITX  5120                 // MM*DD/4/256
#define PREP_TRANSW  (PREP_SPLITX + 1600) // 4 mats x 20 x 20
#define PREP_PASTK   (PREP_TRANSW + 5120) // NB*NH*SP*DHH/4/256
#define PREP_PASTV   (PREP_PASTK + 1280)  // 40 bh x 32 s-tiles

__global__ void prep(const float* __restrict__ x,
                     const float* __restrict__ pK, const float* __restrict__ pV,
                     const float* __restrict__ wq, const float* __restrict__ wk,
                     const float* __restrict__ wv, const float* __restrict__ wo,
                     u16* __restrict__ xh, u16* __restrict__ xl,
                     u16* __restrict__ wqkvh, u16* __restrict__ wqkvl,
                     u16* __restrict__ wot,
                     float* __restrict__ dK, u16* __restrict__ Kh,
                     u16* __restrict__ Kl,
                     float* __restrict__ dV, u16* __restrict__ Vt) {
  __shared__ __align__(16) char smem[16640];  // max(transw 64*65*4, pastv 64*72*2)
  int bid = blockIdx.x, tid = threadIdx.x;
  if (bid < PREP_SPLITX) {
    // ---- splitx ----
    int i = bid * 256 + tid;
    float4 v = ((const float4*)x)[i];
    ushort4 hi, lo;
    hi.x = f2bf(v.x); lo.x = f2bf(v.x - bf2f(hi.x));
    hi.y = f2bf(v.y); lo.y = f2bf(v.y - bf2f(hi.y));
    hi.z = f2bf(v.z); lo.z = f2bf(v.z - bf2f(hi.z));
    hi.w = f2bf(v.w); lo.w = f2bf(v.w - bf2f(hi.w));
    ((ushort4*)xh)[i] = hi;
    ((ushort4*)xl)[i] = lo;
  } else if (bid < PREP_TRANSW) {
    // ---- transw ----
    float (*tile)[65] = (float(*)[65])smem;
    int f = bid - PREP_SPLITX;
    int mat = f / 400, rem = f % 400;
    int k0 = (rem / 20) * 64, n0 = (rem % 20) * 64;
    const float* src = mat == 0 ? wq : mat == 1 ? wk : mat == 2 ? wv : wo;
#pragma unroll
    for (int rep = 0; rep < 16; ++rep) {
      int id = rep * 256 + tid;
      int kl = id >> 6, nl = id & 63;
      tile[nl][kl] = src[(k0 + kl) * DD + n0 + nl];
    }
    __syncthreads();
#pragma unroll
    for (int rep = 0; rep < 16; ++rep) {
      int id = rep * 256 + tid;
      int nl = id >> 6, kl = id & 63;
      float v = tile[nl][kl];
      u16 hi = f2bf(v);
      if (mat < 3) {
        int idx = (mat * DD + n0 + nl) * DD + k0 + kl;
        wqkvh[idx] = hi;
        wqkvl[idx] = f2bf(v - bf2f(hi));
      } else {
        wot[(n0 + nl) * DD + k0 + kl] = hi;
      }
    }
  } else if (bid < PREP_PASTK) {
    // ---- pastk ----
    int i = (bid - PREP_TRANSW) * 256 + tid;
    int e = i * 4;
    int dh = e & 63;
    int s = (e >> 6) & (SP - 1);
    int bh = e >> 17;
    float4 v = *(const float4*)(pK + e);
    int o = (bh * SS + s) * DHH + dh;
    *(float4*)(dK + o) = v;
    ushort4 hi, lo;
    hi.x = f2bf(v.x); lo.x = f2bf(v.x - bf2f(hi.x));
    hi.y = f2bf(v.y); lo.y = f2bf(v.y - bf2f(hi.y));
    hi.z = f2bf(v.z); lo.z = f2bf(v.z - bf2f(hi.z));
    hi.w = f2bf(v.w); lo.w = f2bf(v.w - bf2f(hi.w));
    *(ushort4*)(Kh + o) = hi;
    *(ushort4*)(Kl + o) = lo;
  } else {
    // ---- pastv ----
    u16 (*tile)[72] = (u16(*)[72])smem;
    int bi = bid - PREP_PASTK;
    int bh = bi >> 5, st = bi & 31;
    int s0 = st * 64;
    const float* src = pV + (bh * SP + s0) * DHH;
    float* dst = dV + (bh * SS + s0) * DHH;
#pragma unroll
    for (int rep = 0; rep < 16; ++rep) {
      int id = rep * 256 + tid;
      int sl = id >> 6, dh = id & 63;
      float v = src[sl * DHH + dh];
      dst[sl * DHH + dh] = v;
      tile[dh][sl] = f2bf(v);
    }
    __syncthreads();
    u16* vdst = Vt + (bh * DHH) * SS + s0;
#pragma unroll
    for (int rep = 0; rep < 4; ++rep) {
      int id = rep * 256 + tid;
      int dh = id >> 4, s4 = (id & 15) * 4;
      ushort4 vv;
      vv.x = tile[dh][s4];     vv.y = tile[dh][s4 + 1];
      vv.z = tile[dh][s4 + 2]; vv.w = tile[dh][s4 + 3];
      *(ushort4*)(vdst + dh * SS + s4) = vv;
    }
  }
}

// ---------------- fused QKV split GEMM: [4096,1280] x [1280,3840] ----------
// BK=32, double-buffered LDS, counted-wait pipeline.
// Q,K columns: 3-pass split bf16. V columns: 1-pass.
__launch_bounds__(256, 2)
__global__ void gemm_qkv(const u16* __restrict__ xh, const u16* __restrict__ xl,
                         const u16* __restrict__ wh, const u16* __restrict__ wl,
                         u16* __restrict__ Qh, u16* __restrict__ Ql,
                         u16* __restrict__ Kh, u16* __restrict__ Kl,
                         u16* __restrict__ Vt,
                         float* __restrict__ dK, float* __restrict__ dV) {
  __shared__ __align__(16) char sm[65536];  // 2 bufs x {Ah,Al,Bh,Bl} x 8KB
  int tid = threadIdx.x, lane = tid & 63, w = tid >> 6;
  int wm = w >> 1, wn = w & 1;
  int r15 = lane & 15, grp = lane >> 4;
  int mBase = blockIdx.x * 128;
  int by = blockIdx.y;
  int nGlob = by * 128;
  const bool split = (by < 20);
  f32x4 acc[4][4] = {};
  int id0 = tid, id1 = 256 + tid;
  int r0 = id0 >> 2, c0 = id0 & 3;
  int r1 = id1 >> 2, c1 = id1 & 3;
  int so0 = r0 * DD + (c0 ^ (r0 & 3)) * 8;
  int so1 = r1 * DD + (c1 ^ (r1 & 3)) * 8;
  const u16* aH = xh + mBase * DD;
  const u16* aL = xl + mBase * DD;
  const u16* bH = wh + nGlob * DD;
  const u16* bL = wl + nGlob * DD;
  int do0 = id0 * 16, do1 = id1 * 16;

  auto stage = [&](int buf, int k0) {
    char* b = sm + buf * 32768;
    gload16(aH + k0 + so0, b + do0);
    gload16(aH + k0 + so1, b + do1);
    gload16(bH + k0 + so0, b + 16384 + do0);
    gload16(bH + k0 + so1, b + 16384 + do1);
    if (split) {
      gload16(aL + k0 + so0, b + 8192 + do0);
      gload16(aL + k0 + so1, b + 8192 + do1);
      gload16(bL + k0 + so0, b + 24576 + do0);
      gload16(bL + k0 + so1, b + 24576 + do1);
    }
  };
  auto compute = [&](int buf) {
    const char* b = sm + buf * 32768;
    bf16x8 fah[4], fal[4], fbh[4], fbl[4];
#pragma unroll
    for (int i = 0; i < 4; ++i) {
      fah[i] = frag32(b, wm * 64 + i * 16 + r15, grp);
      fbh[i] = frag32(b + 16384, wn * 64 + i * 16 + r15, grp);
      if (split) {
        fal[i] = frag32(b + 8192, wm * 64 + i * 16 + r15, grp);
        fbl[i] = frag32(b + 24576, wn * 64 + i * 16 + r15, grp);
      }
    }
    __builtin_amdgcn_s_setprio(1);
    if (split) {
#pragma unroll
      for (int i = 0; i < 4; ++i)
#pragma unroll
        for (int j = 0; j < 4; ++j) {
          acc[i][j] = mfma16(fah[i], fbh[j], acc[i][j]);
          acc[i][j] = mfma16(fah[i], fbl[j], acc[i][j]);
          acc[i][j] = mfma16(fal[i], fbh[j], acc[i][j]);
        }
    } else {
#pragma unroll
      for (int i = 0; i < 4; ++i)
#pragma unroll
        for (int j = 0; j < 4; ++j)
          acc[i][j] = mfma16(fah[i], fbh[j], acc[i][j]);
    }
    __builtin_amdgcn_s_setprio(0);
  };

  stage(0, 0);
  VMCNT0(); BAR();
#pragma unroll 2
  for (int step = 0; step < 39; ++step) {
    stage((step + 1) & 1, (step + 1) * 32);
    compute(step & 1);
    VMCNT0(); BAR();
  }
  compute(1);  // step 39

  int proj = by / 10;
  int nb = (by % 10) * 128 + wn * 64;
#pragma unroll
  for (int i = 0; i < 4; ++i)
#pragma unroll
    for (int j = 0; j < 4; ++j)
#pragma unroll
      for (int r = 0; r < 4; ++r) {
        int m = mBase + wm * 64 + i * 16 + grp * 4 + r;
        int n = nb + j * 16 + r15;
        float v = acc[i][j][r];
        int b = m >> 11, t = m & 2047;
        int h = n >> 6, dh = n & 63;
        int bhh = b * NH + h;
        if (proj == 0) {
          float q = v * 0.180336880111f;  // 1/8 * log2(e): exp2-domain softmax
          u16 hi = f2bf(q);
          int idx = (bhh * TT + t) * DHH + dh;
          Qh[idx] = hi;
          Ql[idx] = f2bf(q - bf2f(hi));
        } else if (proj == 1) {
          int idx = (bhh * SS + SP + t) * DHH + dh;
          dK[idx] = v;
          u16 hi = f2bf(v);
          Kh[idx] = hi;
          Kl[idx] = f2bf(v - bf2f(hi));
        } else {
          int idx = (bhh * SS + SP + t) * DHH + dh;
          dV[idx] = v;
          Vt[(bhh * DHH + dh) * SS + SP + t] = f2bf(v);
        }
      }
}

// ---------------- flash attention (R13-proven, unchanged) ----------------
// 128 q-rows/block (4 waves x 32), S in 64-chunks, XCD-clustered bh.
// Hi-first skip + 3-pass refine; lrun scalar accumulation; bc-LDS broadcasts.
__launch_bounds__(256, 3)
__global__ void attn(const u16* __restrict__ Qh, const u16* __restrict__ Ql,
                     const u16* __restrict__ Kh, const u16* __restrict__ Kl,
                     const u16* __restrict__ Vt, u16* __restrict__ ao) {
  __shared__ __align__(16) char Ks[8192];
  __shared__ __align__(16) char Kls[8192];
  __shared__ __align__(16) char Vs[8192];
  __shared__ __align__(16) u16 Pw[4][2][16][72];
  __shared__ __align__(16) float bc[4][16];
  int d = blockIdx.x;
  // XCD swizzle: cluster each bh's 16 q-blocks on one XCD (5 bh per XCD)
  int xcd = d & 7, sl = d >> 3;
  int bh = xcd * 5 + (sl >> 4);
  int q0 = (sl & 15) * 128;
  int tid = threadIdx.x, lane = tid & 63, w = tid >> 6;
  int r15 = lane & 15, grp = lane >> 4;
  int qbase = q0 + w * 32;
  bf16x8 fqh[2][2], fql[2][2];
#pragma unroll
  for (int qt = 0; qt < 2; ++qt) {
    int qrow = qbase + qt * 16 + r15;
    const u16* qb = Qh + (bh * TT + qrow) * DHH + grp * 8;
    const u16* qbl = Ql + (bh * TT + qrow) * DHH + grp * 8;
    fqh[qt][0] = *(const bf16x8*)qb;   fqh[qt][1] = *(const bf16x8*)(qb + 32);
    fql[qt][0] = *(const bf16x8*)qbl;  fql[qt][1] = *(const bf16x8*)(qbl + 32);
  }
  float mrun[2] = {-1e30f, -1e30f};
  float lrun[2] = {0.f, 0.f};
  f32x4 oacc[2][4] = {};
  int id0 = tid, id1 = 256 + tid;
  int r0 = id0 >> 3, c0 = id0 & 7;
  int r1 = id1 >> 3, c1 = id1 & 7;
  const u16* kh0 = Kh + bh * SS * DHH + r0 * DHH + (c0 ^ (r0 & 7)) * 8;
  const u16* kh1 = Kh + bh * SS * DHH + r1 * DHH + (c1 ^ (r1 & 7)) * 8;
  const u16* kl0 = Kl + bh * SS * DHH + r0 * DHH + (c0 ^ (r0 & 7)) * 8;
  const u16* kl1 = Kl + bh * SS * DHH + r1 * DHH + (c1 ^ (r1 & 7)) * 8;
  const u16* v0 = Vt + bh * DHH * SS + r0 * SS + (c0 ^ (r0 & 7)) * 8;
  const u16* v1 = Vt + bh * DHH * SS + r1 * SS + (c1 ^ (r1 & 7)) * 8;
  char* dK0 = Ks + id0 * 16;  char* dK1 = Ks + id1 * 16;
  char* dL0 = Kls + id0 * 16; char* dL1 = Kls + id1 * 16;
  char* dV0 = Vs + id0 * 16;  char* dV1 = Vs + id1 * 16;

  for (int it = 0; it < SS / 64; ++it) {
    gload16(kh0, dK0); gload16(kh1, dK1);
    gload16(kl0, dL0); gload16(kl1, dL1);
    gload16(v0, dV0);  gload16(v1, dV1);
    kh0 += 64 * DHH; kh1 += 64 * DHH;
    kl0 += 64 * DHH; kl1 += 64 * DHH;
    v0 += 64; v1 += 64;
    __syncthreads();
    // ---- hi-only QK^T ----
    f32x4 st[2][4];
    __builtin_amdgcn_s_setprio(1);
#pragma unroll
    for (int kt = 0; kt < 4; ++kt) {
      bf16x8 k0f = frag_swz(Ks, kt * 16 + r15, grp);
      bf16x8 k1f = frag_swz(Ks, kt * 16 + r15, 4 + grp);
#pragma unroll
      for (int qt = 0; qt < 2; ++qt) {
        f32x4 a = {0.f, 0.f, 0.f, 0.f};
        a = mfma16(k0f, fqh[qt][0], a);
        a = mfma16(k1f, fqh[qt][1], a);
        st[qt][kt] = a;
      }
    }
    __builtin_amdgcn_s_setprio(0);
    // chunk max of hi scores per q-col
    float cm[2];
#pragma unroll
    for (int qt = 0; qt < 2; ++qt) {
      float c = max16(st[qt]);
      c = fmaxf(c, __shfl_xor(c, 16));
      c = fmaxf(c, __shfl_xor(c, 32));
      cm[qt] = c;
    }
    bool act = (!__all(cm[0] <= mrun[0] - 88.f)) |
               (!__all(cm[1] <= mrun[1] - 88.f));
    if (act) {
      // ---- lo refine: re-read K-hi + K-lo frags from LDS ----
      __builtin_amdgcn_s_setprio(1);
#pragma unroll
      for (int kt = 0; kt < 4; ++kt) {
        bf16x8 k0f = frag_swz(Ks, kt * 16 + r15, grp);
        bf16x8 k1f = frag_swz(Ks, kt * 16 + r15, 4 + grp);
        bf16x8 l0f = frag_swz(Kls, kt * 16 + r15, grp);
        bf16x8 l1f = frag_swz(Kls, kt * 16 + r15, 4 + grp);
#pragma unroll
        for (int qt = 0; qt < 2; ++qt) {
          st[qt][kt] = mfma16(l0f, fqh[qt][0], st[qt][kt]);
          st[qt][kt] = mfma16(k0f, fql[qt][0], st[qt][kt]);
          st[qt][kt] = mfma16(l1f, fqh[qt][1], st[qt][kt]);
          st[qt][kt] = mfma16(k1f, fql[qt][1], st[qt][kt]);
        }
      }
      __builtin_amdgcn_s_setprio(0);
      // ---- softmax + pack per q-tile ----
#pragma unroll
      for (int qt = 0; qt < 2; ++qt) {
        if (!__all(cm[qt] <= mrun[qt] + 8.f)) {  // defer-max rescale
          float mnew = fmaxf(mrun[qt], cm[qt]);
          float sc = fexp2(mrun[qt] - mnew);
          lrun[qt] *= sc;
          mrun[qt] = mnew;
          if (grp == 0) bc[w][r15] = sc;
          f32x4 scv = *(const f32x4*)&bc[w][grp * 4];
#pragma unroll
          for (int dd = 0; dd < 4; ++dd) {
            oacc[qt][dd][0] *= scv[0]; oacc[qt][dd][1] *= scv[1];
            oacc[qt][dd][2] *= scv[2]; oacc[qt][dd][3] *= scv[3];
          }
        }
        float m = mrun[qt];
        float ps = 0.f;
#pragma unroll
        for (int kt = 0; kt < 4; ++kt)
#pragma unroll
          for (int r = 0; r < 4; ++r) {
            float p = fexp2(st[qt][kt][r] - m);
            st[qt][kt][r] = p;
            ps += p;
          }
        ps += __shfl_xor(ps, 16);
        ps += __shfl_xor(ps, 32);
        lrun[qt] += ps;
#pragma unroll
        for (int kt = 0; kt < 4; ++kt) {
          u32 w0 = cvtpk(st[qt][kt][0], st[qt][kt][1]);
          u32 w1 = cvtpk(st[qt][kt][2], st[qt][kt][3]);
          uint2 pk = {w0, w1};
          *(uint2*)&Pw[w][qt][r15][kt * 16 + grp * 4] = pk;
        }
      }
      // ---- PV: V frags shared across both q-tiles ----
      bf16x8 pa[2][2];
#pragma unroll
      for (int qt = 0; qt < 2; ++qt) {
        pa[qt][0] = *(const bf16x8*)&Pw[w][qt][r15][grp * 8];
        pa[qt][1] = *(const bf16x8*)&Pw[w][qt][r15][32 + grp * 8];
      }
      __builtin_amdgcn_s_setprio(1);
#pragma unroll
      for (int dd = 0; dd < 4; ++dd) {
        bf16x8 vf0 = frag_swz(Vs, dd * 16 + r15, grp);
        bf16x8 vf1 = frag_swz(Vs, dd * 16 + r15, 4 + grp);
#pragma unroll
        for (int qt = 0; qt < 2; ++qt) {
          oacc[qt][dd] = mfma16(pa[qt][0], vf0, oacc[qt][dd]);
          oacc[qt][dd] = mfma16(pa[qt][1], vf1, oacc[qt][dd]);
        }
      }
      __builtin_amdgcn_s_setprio(0);
    }
    __syncthreads();
  }
  int b = bh / NH, h = bh % NH;
#pragma unroll
  for (int qt = 0; qt < 2; ++qt) {
    float inv = 1.0f / lrun[qt];
    if (grp == 0) bc[w][r15] = inv;
    f32x4 li = *(const f32x4*)&bc[w][grp * 4];
#pragma unroll
    for (int dd = 0; dd < 4; ++dd)
#pragma unroll
      for (int r = 0; r < 4; ++r) {
        int q = qbase + qt * 16 + grp * 4 + r;
        int col = h * DHH + dd * 16 + r15;
        ao[(b * TT + q) * DD + col] = f2bf(oacc[qt][dd][r] * li[r]);
      }
  }
}

// ---------------- out = values @ W_o (single bf16) ----------------
// BK=32 double-buffered counted-wait pipeline (clone of gemm_qkv split=false).
__launch_bounds__(256, 3)
__global__ void gemm_out(const u16* __restrict__ ao, const u16* __restrict__ wot,
                         float* __restrict__ out) {
  __shared__ __align__(16) char sm[32768];  // 2 bufs x {A 8KB, B 8KB}
  int tid = threadIdx.x, lane = tid & 63, w = tid >> 6;
  int wm = w >> 1, wn = w & 1;
  int r15 = lane & 15, grp = lane >> 4;
  int mBase = blockIdx.x * 128, nBase = blockIdx.y * 128;
  f32x4 acc[4][4] = {};
  int id0 = tid, id1 = 256 + tid;
  int r0 = id0 >> 2, c0 = id0 & 3;
  int r1 = id1 >> 2, c1 = id1 & 3;
  int so0 = r0 * DD + (c0 ^ (r0 & 3)) * 8;
  int so1 = r1 * DD + (c1 ^ (r1 & 3)) * 8;
  const u16* aP = ao + mBase * DD;
  const u16* bP = wot + nBase * DD;
  int do0 = id0 * 16, do1 = id1 * 16;

  auto stage = [&](int buf, int k0) {
    char* b = sm + buf * 16384;
    gload16(aP + k0 + so0, b + do0);
    gload16(aP + k0 + so1, b + do1);
    gload16(bP + k0 + so0, b + 8192 + do0);
    gload16(bP + k0 + so1, b + 8192 + do1);
  };
  auto compute = [&](int buf) {
    const char* b = sm + buf * 16384;
    bf16x8 fa[4], fb[4];
#pragma unroll
    for (int i = 0; i < 4; ++i) {
      fa[i] = frag32(b, wm * 64 + i * 16 + r15, grp);
      fb[i] = frag32(b + 8192, wn * 64 + i * 16 + r15, grp);
    }
    __builtin_amdgcn_s_setprio(1);
#pragma unroll
    for (int i = 0; i < 4; ++i)
#pragma unroll
      for (int j = 0; j < 4; ++j)
        acc[i][j] = mfma16(fa[i], fb[j], acc[i][j]);
    __builtin_amdgcn_s_setprio(0);
  };

  stage(0, 0);
  VMCNT0(); BAR();
#pragma unroll 2
  for (int step = 0; step < 39; ++step) {
    stage((step + 1) & 1, (step + 1) * 32);
    compute(step & 1);
    VMCNT0(); BAR();
  }
  compute(1);  // step 39

#pragma unroll
  for (int i = 0; i < 4; ++i)
#pragma unroll
    for (int j = 0; j < 4; ++j)
#pragma unroll
      for (int r = 0; r < 4; ++r) {
        int m = mBase + wm * 64 + i * 16 + grp * 4 + r;
        int n = nBase + wn * 64 + j * 16 + r15;
        out[m * DD + n] = acc[i][j][r];
      }
}

extern "C" void kernel_launch(void* const* d_in, const int* in_sizes, int n_in,
                              void* d_out, int out_size, void* d_ws, size_t ws_size,
                              hipStream_t stream) {
  const float* x  = (const float*)d_in[0];
  const float* pK = (const float*)d_in[1];
  const float* pV = (const float*)d_in[2];
  const float* wq = (const float*)d_in[3];
  const float* wk = (const float*)d_in[4];
  const float* wv = (const float*)d_in[5];
  const float* wo = (const float*)d_in[6];

  float* out = (float*)d_out;            // [B,T,D]
  float* dK  = out + NB * TT * DD;       // [B,H,S,DH]
  float* dV  = dK + NB * NH * SS * DHH;  // [B,H,S,DH]

  u16* xh    = (u16*)d_ws;               // [4096][1280]
  u16* xl    = xh + MM * DD;
  u16* wqkvh = xl + MM * DD;             // [3840][1280] transposed weights
  u16* wqkvl = wqkvh + 3 * DD * DD;
  u16* wot   = wqkvl + 3 * DD * DD;      // [1280][1280]
  u16* Qh    = wot + DD * DD;            // [B,H,T,DH] (pre-scaled, exp2 domain)
  u16* Ql    = Qh + MM * DD;
  u16* Kh    = Ql + MM * DD;             // [B,H,S,DH]
  u16* Kl    = Kh + NB * NH * SS * DHH;
  u16* Vt    = Kl + NB * NH * SS * DHH;  // [B,H,DH,S]
  u16* ao    = xh;                       // alias: x dead after gemm_qkv

  prep<<<dim3(PREP_PASTV), 256, 0, stream>>>(x, pK, pV, wq, wk, wv, wo,
                                             xh, xl, wqkvh, wqkvl, wot,
                                             dK, Kh, Kl, dV, Vt);
  gemm_qkv<<<dim3(32, 30), 256, 0, stream>>>(xh, xl, wqkvh, wqkvl,
                                             Qh, Ql, Kh, Kl, Vt, dK, dV);
  attn<<<dim3(NB * NH * (TT / 128)), 256, 0, stream>>>(Qh, Ql, Kh, Kl, Vt, ao);
  gemm_out<<<dim3(32, 10), 256, 0, stream>>>(ao, wot, out);
}

// Round 18
// 366.930 us; speedup vs baseline: 1.6122x; 1.0075x over previous
//
#include <hip/hip_runtime.h>

#define NB 2
#define NH 20
#define TT 2048
#define DD 1280
#define DHH 64
#define SP 2048
#define SS 4096
#define MM (NB*TT)

typedef __attribute__((ext_vector_type(8))) short bf16x8;
typedef __attribute__((ext_vector_type(4))) float f32x4;
typedef unsigned short u16;
typedef unsigned int u32;

__device__ __forceinline__ f32x4 mfma16(bf16x8 a, bf16x8 b, f32x4 c) {
  return __builtin_amdgcn_mfma_f32_16x16x32_bf16(a, b, c, 0, 0, 0);
}

// round-to-nearest-even f32 -> bf16 bits
__device__ __forceinline__ u16 f2bf(float f) {
  u32 x = __builtin_bit_cast(u32, f);
  x += 0x7fffu + ((x >> 16) & 1u);
  return (u16)(x >> 16);
}
__device__ __forceinline__ float bf2f(u16 u) {
  u32 x = ((u32)u) << 16;
  return __builtin_bit_cast(float, x);
}

__device__ __forceinline__ float fexp2(float x) {
#if __has_builtin(__builtin_amdgcn_exp2f)
  return __builtin_amdgcn_exp2f(x);
#else
  return exp2f(x);
#endif
}

__device__ __forceinline__ u32 cvtpk(float lo, float hi) {
  u32 r;
  asm("v_cvt_pk_bf16_f32 %0, %1, %2" : "=v"(r) : "v"(lo), "v"(hi));
  return r;
}

__device__ __forceinline__ float vmax3(float a, float b, float c) {
  float d;
  asm("v_max3_f32 %0, %1, %2, %3" : "=v"(d) : "v"(a), "v"(b), "v"(c));
  return d;
}
// max of 16 f32 (4x f32x4) via max3 tree
__device__ __forceinline__ float max16(const f32x4* st) {
  float m0 = vmax3(st[0][0], st[0][1], st[0][2]);
  float m1 = vmax3(st[0][3], st[1][0], st[1][1]);
  float m2 = vmax3(st[1][2], st[1][3], st[2][0]);
  float m3 = vmax3(st[2][1], st[2][2], st[2][3]);
  float m4 = vmax3(st[3][0], st[3][1], st[3][2]);
  float m5 = vmax3(m0, m1, st[3][3]);
  float m6 = vmax3(m2, m3, m4);
  return fmaxf(m5, m6);
}

#define VMCNT0() asm volatile("s_waitcnt vmcnt(0)" ::: "memory")
#define BAR() __builtin_amdgcn_s_barrier()

__device__ __forceinline__ void gload16(const u16* src, char* ldst) {
  __builtin_amdgcn_global_load_lds(
      (const __attribute__((address_space(1))) u32*)src,
      (__attribute__((address_space(3))) u32*)ldst, 16, 0, 0);
}

// chunk cc (k cc*8..cc*8+7) of `row`, 128B rows
__device__ __forceinline__ bf16x8 frag_swz(const char* lds, int row, int cc) {
  return *(const bf16x8*)(lds + row * 128 + ((cc ^ (row & 7)) << 4));
}
// 64B rows (BK=32 tiles)
__device__ __forceinline__ bf16x8 frag32(const char* lds, int row, int cc) {
  return *(const bf16x8*)(lds + row * 64 + ((cc ^ (row & 3)) << 4));
}

// ---------------- prep: splitx | transw (gemm_qkv's inputs only) -----------
#define PREP_SPLITX  5120                 // MM*DD/4/256
#define PREP_TRANSW  (PREP_SPLITX + 1600) // 4 mats x 20 x 20

__global__ void prep(const float* __restrict__ x,
                     const float* __restrict__ wq, const float* __restrict__ wk,
                     const float* __restrict__ wv, const float* __restrict__ wo,
                     u16* __restrict__ xh, u16* __restrict__ xl,
                     u16* __restrict__ wqkvh, u16* __restrict__ wqkvl,
                     u16* __restrict__ wot) {
  __shared__ __align__(16) float tile[64][65];
  int bid = blockIdx.x, tid = threadIdx.x;
  if (bid < PREP_SPLITX) {
    // ---- splitx ----
    int i = bid * 256 + tid;
    float4 v = ((const float4*)x)[i];
    ushort4 hi, lo;
    hi.x = f2bf(v.x); lo.x = f2bf(v.x - bf2f(hi.x));
    hi.y = f2bf(v.y); lo.y = f2bf(v.y - bf2f(hi.y));
    hi.z = f2bf(v.z); lo.z = f2bf(v.z - bf2f(hi.z));
    hi.w = f2bf(v.w); lo.w = f2bf(v.w - bf2f(hi.w));
    ((ushort4*)xh)[i] = hi;
    ((ushort4*)xl)[i] = lo;
  } else {
    // ---- transw ----
    int f = bid - PREP_SPLITX;
    int mat = f / 400, rem = f % 400;
    int k0 = (rem / 20) * 64, n0 = (rem % 20) * 64;
    const float* src = mat == 0 ? wq : mat == 1 ? wk : mat == 2 ? wv : wo;
#pragma unroll
    for (int rep = 0; rep < 16; ++rep) {
      int id = rep * 256 + tid;
      int kl = id >> 6, nl = id & 63;
      tile[nl][kl] = src[(k0 + kl) * DD + n0 + nl];
    }
    __syncthreads();
#pragma unroll
    for (int rep = 0; rep < 16; ++rep) {
      int id = rep * 256 + tid;
      int nl = id >> 6, kl = id & 63;
      float v = tile[nl][kl];
      u16 hi = f2bf(v);
      if (mat < 3) {
        int idx = (mat * DD + n0 + nl) * DD + k0 + kl;
        wqkvh[idx] = hi;
        wqkvl[idx] = f2bf(v - bf2f(hi));
      } else {
        wot[(n0 + nl) * DD + k0 + kl] = hi;
      }
    }
  }
}

// ---------------- fused QKV split GEMM + pastK/pastV streaming -------------
// bid < 960: BK=32 double-buffered GEMM (bx=bid&31, by=bid>>5), unchanged.
// bid 960..6080: pastk (f32 copy + hi/lo bf16). bid 6080..7360: pastv
// (f32 copy + bf16 transpose). Past writes (s<SP) disjoint from GEMM's new
// K/V writes (s>=SP); both consumed only by the later attn dispatch.
#define GQ_GEMM   960
#define GQ_PASTK  (GQ_GEMM + 5120)
#define GQ_PASTV  (GQ_PASTK + 1280)

__launch_bounds__(256, 2)
__global__ void gemm_qkv(const u16* __restrict__ xh, const u16* __restrict__ xl,
                         const u16* __restrict__ wh, const u16* __restrict__ wl,
                         const float* __restrict__ pK, const float* __restrict__ pV,
                         u16* __restrict__ Qh, u16* __restrict__ Ql,
                         u16* __restrict__ Kh, u16* __restrict__ Kl,
                         u16* __restrict__ Vt,
                         float* __restrict__ dK, float* __restrict__ dV) {
  __shared__ __align__(16) char sm[65536];  // GEMM: 2 bufs x {Ah,Al,Bh,Bl} x 8KB
  int bid = blockIdx.x;
  int tid = threadIdx.x;
  if (bid >= GQ_GEMM) {
    if (bid < GQ_PASTK) {
      // ---- pastk ----
      int i = (bid - GQ_GEMM) * 256 + tid;
      int e = i * 4;
      int dh = e & 63;
      int s = (e >> 6) & (SP - 1);
      int bh = e >> 17;
      float4 v = *(const float4*)(pK + e);
      int o = (bh * SS + s) * DHH + dh;
      *(float4*)(dK + o) = v;
      ushort4 hi, lo;
      hi.x = f2bf(v.x); lo.x = f2bf(v.x - bf2f(hi.x));
      hi.y = f2bf(v.y); lo.y = f2bf(v.y - bf2f(hi.y));
      hi.z = f2bf(v.z); lo.z = f2bf(v.z - bf2f(hi.z));
      hi.w = f2bf(v.w); lo.w = f2bf(v.w - bf2f(hi.w));
      *(ushort4*)(Kh + o) = hi;
      *(ushort4*)(Kl + o) = lo;
    } else {
      // ---- pastv ----
      u16 (*tile)[72] = (u16(*)[72])sm;
      int bi = bid - GQ_PASTK;
      int bh = bi >> 5, st = bi & 31;
      int s0 = st * 64;
      const float* src = pV + (bh * SP + s0) * DHH;
      float* dst = dV + (bh * SS + s0) * DHH;
#pragma unroll
      for (int rep = 0; rep < 16; ++rep) {
        int id = rep * 256 + tid;
        int sl = id >> 6, dh = id & 63;
        float v = src[sl * DHH + dh];
        dst[sl * DHH + dh] = v;
        tile[dh][sl] = f2bf(v);
      }
      __syncthreads();
      u16* vdst = Vt + (bh * DHH) * SS + s0;
#pragma unroll
      for (int rep = 0; rep < 4; ++rep) {
        int id = rep * 256 + tid;
        int dh = id >> 4, s4 = (id & 15) * 4;
        ushort4 vv;
        vv.x = tile[dh][s4];     vv.y = tile[dh][s4 + 1];
        vv.z = tile[dh][s4 + 2]; vv.w = tile[dh][s4 + 3];
        *(ushort4*)(vdst + dh * SS + s4) = vv;
      }
    }
    return;
  }
  // ---- GEMM path (unchanged body) ----
  int lane = tid & 63, w = tid >> 6;
  int wm = w >> 1, wn = w & 1;
  int r15 = lane & 15, grp = lane >> 4;
  int mBase = (bid & 31) * 128;
  int by = bid >> 5;
  int nGlob = by * 128;
  const bool split = (by < 20);
  f32x4 acc[4][4] = {};
  int id0 = tid, id1 = 256 + tid;
  int r0 = id0 >> 2, c0 = id0 & 3;
  int r1 = id1 >> 2, c1 = id1 & 3;
  int so0 = r0 * DD + (c0 ^ (r0 & 3)) * 8;
  int so1 = r1 * DD + (c1 ^ (r1 & 3)) * 8;
  const u16* aH = xh + mBase * DD;
  const u16* aL = xl + mBase * DD;
  const u16* bH = wh + nGlob * DD;
  const u16* bL = wl + nGlob * DD;
  int do0 = id0 * 16, do1 = id1 * 16;

  auto stage = [&](int buf, int k0) {
    char* b = sm + buf * 32768;
    gload16(aH + k0 + so0, b + do0);
    gload16(aH + k0 + so1, b + do1);
    gload16(bH + k0 + so0, b + 16384 + do0);
    gload16(bH + k0 + so1, b + 16384 + do1);
    if (split) {
      gload16(aL + k0 + so0, b + 8192 + do0);
      gload16(aL + k0 + so1, b + 8192 + do1);
      gload16(bL + k0 + so0, b + 24576 + do0);
      gload16(bL + k0 + so1, b + 24576 + do1);
    }
  };
  auto compute = [&](int buf) {
    const char* b = sm + buf * 32768;
    bf16x8 fah[4], fal[4], fbh[4], fbl[4];
#pragma unroll
    for (int i = 0; i < 4; ++i) {
      fah[i] = frag32(b, wm * 64 + i * 16 + r15, grp);
      fbh[i] = frag32(b + 16384, wn * 64 + i * 16 + r15, grp);
      if (split) {
        fal[i] = frag32(b + 8192, wm * 64 + i * 16 + r15, grp);
        fbl[i] = frag32(b + 24576, wn * 64 + i * 16 + r15, grp);
      }
    }
    __builtin_amdgcn_s_setprio(1);
    if (split) {
#pragma unroll
      for (int i = 0; i < 4; ++i)
#pragma unroll
        for (int j = 0; j < 4; ++j) {
          acc[i][j] = mfma16(fah[i], fbh[j], acc[i][j]);
          acc[i][j] = mfma16(fah[i], fbl[j], acc[i][j]);
          acc[i][j] = mfma16(fal[i], fbh[j], acc[i][j]);
        }
    } else {
#pragma unroll
      for (int i = 0; i < 4; ++i)
#pragma unroll
        for (int j = 0; j < 4; ++j)
          acc[i][j] = mfma16(fah[i], fbh[j], acc[i][j]);
    }
    __builtin_amdgcn_s_setprio(0);
  };

  stage(0, 0);
  VMCNT0(); BAR();
#pragma unroll 2
  for (int step = 0; step < 39; ++step) {
    stage((step + 1) & 1, (step + 1) * 32);
    compute(step & 1);
    VMCNT0(); BAR();
  }
  compute(1);  // step 39

  int proj = by / 10;
  int nb = (by % 10) * 128 + wn * 64;
#pragma unroll
  for (int i = 0; i < 4; ++i)
#pragma unroll
    for (int j = 0; j < 4; ++j)
#pragma unroll
      for (int r = 0; r < 4; ++r) {
        int m = mBase + wm * 64 + i * 16 + grp * 4 + r;
        int n = nb + j * 16 + r15;
        float v = acc[i][j][r];
        int b = m >> 11, t = m & 2047;
        int h = n >> 6, dh = n & 63;
        int bhh = b * NH + h;
        if (proj == 0) {
          float q = v * 0.180336880111f;  // 1/8 * log2(e): exp2-domain softmax
          u16 hi = f2bf(q);
          int idx = (bhh * TT + t) * DHH + dh;
          Qh[idx] = hi;
          Ql[idx] = f2bf(q - bf2f(hi));
        } else if (proj == 1) {
          int idx = (bhh * SS + SP + t) * DHH + dh;
          dK[idx] = v;
          u16 hi = f2bf(v);
          Kh[idx] = hi;
          Kl[idx] = f2bf(v - bf2f(hi));
        } else {
          int idx = (bhh * SS + SP + t) * DHH + dh;
          dV[idx] = v;
          Vt[(bhh * DHH + dh) * SS + SP + t] = f2bf(v);
        }
      }
}

// ---------------- flash attention (R13-proven, unchanged) ----------------
// 128 q-rows/block (4 waves x 32), S in 64-chunks, XCD-clustered bh.
// Hi-first skip + 3-pass refine; lrun scalar accumulation; bc-LDS broadcasts.
__launch_bounds__(256, 3)
__global__ void attn(const u16* __restrict__ Qh, const u16* __restrict__ Ql,
                     const u16* __restrict__ Kh, const u16* __restrict__ Kl,
                     const u16* __restrict__ Vt, u16* __restrict__ ao) {
  __shared__ __align__(16) char Ks[8192];
  __shared__ __align__(16) char Kls[8192];
  __shared__ __align__(16) char Vs[8192];
  __shared__ __align__(16) u16 Pw[4][2][16][72];
  __shared__ __align__(16) float bc[4][16];
  int d = blockIdx.x;
  // XCD swizzle: cluster each bh's 16 q-blocks on one XCD (5 bh per XCD)
  int xcd = d & 7, sl = d >> 3;
  int bh = xcd * 5 + (sl >> 4);
  int q0 = (sl & 15) * 128;
  int tid = threadIdx.x, lane = tid & 63, w = tid >> 6;
  int r15 = lane & 15, grp = lane >> 4;
  int qbase = q0 + w * 32;
  bf16x8 fqh[2][2], fql[2][2];
#pragma unroll
  for (int qt = 0; qt < 2; ++qt) {
    int qrow = qbase + qt * 16 + r15;
    const u16* qb = Qh + (bh * TT + qrow) * DHH + grp * 8;
    const u16* qbl = Ql + (bh * TT + qrow) * DHH + grp * 8;
    fqh[qt][0] = *(const bf16x8*)qb;   fqh[qt][1] = *(const bf16x8*)(qb + 32);
    fql[qt][0] = *(const bf16x8*)qbl;  fql[qt][1] = *(const bf16x8*)(qbl + 32);
  }
  float mrun[2] = {-1e30f, -1e30f};
  float lrun[2] = {0.f, 0.f};
  f32x4 oacc[2][4] = {};
  int id0 = tid, id1 = 256 + tid;
  int r0 = id0 >> 3, c0 = id0 & 7;
  int r1 = id1 >> 3, c1 = id1 & 7;
  const u16* kh0 = Kh + bh * SS * DHH + r0 * DHH + (c0 ^ (r0 & 7)) * 8;
  const u16* kh1 = Kh + bh * SS * DHH + r1 * DHH + (c1 ^ (r1 & 7)) * 8;
  const u16* kl0 = Kl + bh * SS * DHH + r0 * DHH + (c0 ^ (r0 & 7)) * 8;
  const u16* kl1 = Kl + bh * SS * DHH + r1 * DHH + (c1 ^ (r1 & 7)) * 8;
  const u16* v0 = Vt + bh * DHH * SS + r0 * SS + (c0 ^ (r0 & 7)) * 8;
  const u16* v1 = Vt + bh * DHH * SS + r1 * SS + (c1 ^ (r1 & 7)) * 8;
  char* dK0 = Ks + id0 * 16;  char* dK1 = Ks + id1 * 16;
  char* dL0 = Kls + id0 * 16; char* dL1 = Kls + id1 * 16;
  char* dV0 = Vs + id0 * 16;  char* dV1 = Vs + id1 * 16;

  for (int it = 0; it < SS / 64; ++it) {
    gload16(kh0, dK0); gload16(kh1, dK1);
    gload16(kl0, dL0); gload16(kl1, dL1);
    gload16(v0, dV0);  gload16(v1, dV1);
    kh0 += 64 * DHH; kh1 += 64 * DHH;
    kl0 += 64 * DHH; kl1 += 64 * DHH;
    v0 += 64; v1 += 64;
    __syncthreads();
    // ---- hi-only QK^T ----
    f32x4 st[2][4];
    __builtin_amdgcn_s_setprio(1);
#pragma unroll
    for (int kt = 0; kt < 4; ++kt) {
      bf16x8 k0f = frag_swz(Ks, kt * 16 + r15, grp);
      bf16x8 k1f = frag_swz(Ks, kt * 16 + r15, 4 + grp);
#pragma unroll
      for (int qt = 0; qt < 2; ++qt) {
        f32x4 a = {0.f, 0.f, 0.f, 0.f};
        a = mfma16(k0f, fqh[qt][0], a);
        a = mfma16(k1f, fqh[qt][1], a);
        st[qt][kt] = a;
      }
    }
    __builtin_amdgcn_s_setprio(0);
    // chunk max of hi scores per q-col
    float cm[2];
#pragma unroll
    for (int qt = 0; qt < 2; ++qt) {
      float c = max16(st[qt]);
      c = fmaxf(c, __shfl_xor(c, 16));
      c = fmaxf(c, __shfl_xor(c, 32));
      cm[qt] = c;
    }
    bool act = (!__all(cm[0] <= mrun[0] - 88.f)) |
               (!__all(cm[1] <= mrun[1] - 88.f));
    if (act) {
      // ---- lo refine: re-read K-hi + K-lo frags from LDS ----
      __builtin_amdgcn_s_setprio(1);
#pragma unroll
      for (int kt = 0; kt < 4; ++kt) {
        bf16x8 k0f = frag_swz(Ks, kt * 16 + r15, grp);
        bf16x8 k1f = frag_swz(Ks, kt * 16 + r15, 4 + grp);
        bf16x8 l0f = frag_swz(Kls, kt * 16 + r15, grp);
        bf16x8 l1f = frag_swz(Kls, kt * 16 + r15, 4 + grp);
#pragma unroll
        for (int qt = 0; qt < 2; ++qt) {
          st[qt][kt] = mfma16(l0f, fqh[qt][0], st[qt][kt]);
          st[qt][kt] = mfma16(k0f, fql[qt][0], st[qt][kt]);
          st[qt][kt] = mfma16(l1f, fqh[qt][1], st[qt][kt]);
          st[qt][kt] = mfma16(k1f, fql[qt][1], st[qt][kt]);
        }
      }
      __builtin_amdgcn_s_setprio(0);
      // ---- softmax + pack per q-tile ----
#pragma unroll
      for (int qt = 0; qt < 2; ++qt) {
        if (!__all(cm[qt] <= mrun[qt] + 8.f)) {  // defer-max rescale
          float mnew = fmaxf(mrun[qt], cm[qt]);
          float sc = fexp2(mrun[qt] - mnew);
          lrun[qt] *= sc;
          mrun[qt] = mnew;
          if (grp == 0) bc[w][r15] = sc;
          f32x4 scv = *(const f32x4*)&bc[w][grp * 4];
#pragma unroll
          for (int dd = 0; dd < 4; ++dd) {
            oacc[qt][dd][0] *= scv[0]; oacc[qt][dd][1] *= scv[1];
            oacc[qt][dd][2] *= scv[2]; oacc[qt][dd][3] *= scv[3];
          }
        }
        float m = mrun[qt];
        float ps = 0.f;
#pragma unroll
        for (int kt = 0; kt < 4; ++kt)
#pragma unroll
          for (int r = 0; r < 4; ++r) {
            float p = fexp2(st[qt][kt][r] - m);
            st[qt][kt][r] = p;
            ps += p;
          }
        ps += __shfl_xor(ps, 16);
        ps += __shfl_xor(ps, 32);
        lrun[qt] += ps;
#pragma unroll
        for (int kt = 0; kt < 4; ++kt) {
          u32 w0 = cvtpk(st[qt][kt][0], st[qt][kt][1]);
          u32 w1 = cvtpk(st[qt][kt][2], st[qt][kt][3]);
          uint2 pk = {w0, w1};
          *(uint2*)&Pw[w][qt][r15][kt * 16 + grp * 4] = pk;
        }
      }
      // ---- PV: V frags shared across both q-tiles ----
      bf16x8 pa[2][2];
#pragma unroll
      for (int qt = 0; qt < 2; ++qt) {
        pa[qt][0] = *(const bf16x8*)&Pw[w][qt][r15][grp * 8];
        pa[qt][1] = *(const bf16x8*)&Pw[w][qt][r15][32 + grp * 8];
      }
      __builtin_amdgcn_s_setprio(1);
#pragma unroll
      for (int dd = 0; dd < 4; ++dd) {
        bf16x8 vf0 = frag_swz(Vs, dd * 16 + r15, grp);
        bf16x8 vf1 = frag_swz(Vs, dd * 16 + r15, 4 + grp);
#pragma unroll
        for (int qt = 0; qt < 2; ++qt) {
          oacc[qt][dd] = mfma16(pa[qt][0], vf0, oacc[qt][dd]);
          oacc[qt][dd] = mfma16(pa[qt][1], vf1, oacc[qt][dd]);
        }
      }
      __builtin_amdgcn_s_setprio(0);
    }
    __syncthreads();
  }
  int b = bh / NH, h = bh % NH;
#pragma unroll
  for (int qt = 0; qt < 2; ++qt) {
    float inv = 1.0f / lrun[qt];
    if (grp == 0) bc[w][r15] = inv;
    f32x4 li = *(const f32x4*)&bc[w][grp * 4];
#pragma unroll
    for (int dd = 0; dd < 4; ++dd)
#pragma unroll
      for (int r = 0; r < 4; ++r) {
        int q = qbase + qt * 16 + grp * 4 + r;
        int col = h * DHH + dd * 16 + r15;
        ao[(b * TT + q) * DD + col] = f2bf(oacc[qt][dd][r] * li[r]);
      }
  }
}

// ---------------- out = values @ W_o (single bf16) ----------------
// BK=32 double-buffered counted-wait pipeline (clone of gemm_qkv split=false).
__launch_bounds__(256, 3)
__global__ void gemm_out(const u16* __restrict__ ao, const u16* __restrict__ wot,
                         float* __restrict__ out) {
  __shared__ __align__(16) char sm[32768];  // 2 bufs x {A 8KB, B 8KB}
  int tid = threadIdx.x, lane = tid & 63, w = tid >> 6;
  int wm = w >> 1, wn = w & 1;
  int r15 = lane & 15, grp = lane >> 4;
  int mBase = blockIdx.x * 128, nBase = blockIdx.y * 128;
  f32x4 acc[4][4] = {};
  int id0 = tid, id1 = 256 + tid;
  int r0 = id0 >> 2, c0 = id0 & 3;
  int r1 = id1 >> 2, c1 = id1 & 3;
  int so0 = r0 * DD + (c0 ^ (r0 & 3)) * 8;
  int so1 = r1 * DD + (c1 ^ (r1 & 3)) * 8;
  const u16* aP = ao + mBase * DD;
  const u16* bP = wot + nBase * DD;
  int do0 = id0 * 16, do1 = id1 * 16;

  auto stage = [&](int buf, int k0) {
    char* b = sm + buf * 16384;
    gload16(aP + k0 + so0, b + do0);
    gload16(aP + k0 + so1, b + do1);
    gload16(bP + k0 + so0, b + 8192 + do0);
    gload16(bP + k0 + so1, b + 8192 + do1);
  };
  auto compute = [&](int buf) {
    const char* b = sm + buf * 16384;
    bf16x8 fa[4], fb[4];
#pragma unroll
    for (int i = 0; i < 4; ++i) {
      fa[i] = frag32(b, wm * 64 + i * 16 + r15, grp);
      fb[i] = frag32(b + 8192, wn * 64 + i * 16 + r15, grp);
    }
    __builtin_amdgcn_s_setprio(1);
#pragma unroll
    for (int i = 0; i < 4; ++i)
#pragma unroll
      for (int j = 0; j < 4; ++j)
        acc[i][j] = mfma16(fa[i], fb[j], acc[i][j]);
    __builtin_amdgcn_s_setprio(0);
  };

  stage(0, 0);
  VMCNT0(); BAR();
#pragma unroll 2
  for (int step = 0; step < 39; ++step) {
    stage((step + 1) & 1, (step + 1) * 32);
    compute(step & 1);
    VMCNT0(); BAR();
  }
  compute(1);  // step 39

#pragma unroll
  for (int i = 0; i < 4; ++i)
#pragma unroll
    for (int j = 0; j < 4; ++j)
#pragma unroll
      for (int r = 0; r < 4; ++r) {
        int m = mBase + wm * 64 + i * 16 + grp * 4 + r;
        int n = nBase + wn * 64 + j * 16 + r15;
        out[m * DD + n] = acc[i][j][r];
      }
}

extern "C" void kernel_launch(void* const* d_in, const int* in_sizes, int n_in,
                              void* d_out, int out_size, void* d_ws, size_t ws_size,
                              hipStream_t stream) {
  const float* x  = (const float*)d_in[0];
  const float* pK = (const float*)d_in[1];
  const float* pV = (const float*)d_in[2];
  const float* wq = (const float*)d_in[3];
  const float* wk = (const float*)d_in[4];
  const float* wv = (const float*)d_in[5];
  const float* wo = (const float*)d_in[6];

  float* out = (float*)d_out;            // [B,T,D]
  float* dK  = out + NB * TT * DD;       // [B,H,S,DH]
  float* dV  = dK + NB * NH * SS * DHH;  // [B,H,S,DH]

  u16* xh    = (u16*)d_ws;               // [4096][1280]
  u16* xl    = xh + MM * DD;
  u16* wqkvh = xl + MM * DD;             // [3840][1280] transposed weights
  u16* wqkvl = wqkvh + 3 * DD * DD;
  u16* wot   = wqkvl + 3 * DD * DD;      // [1280][1280]
  u16* Qh    = wot + DD * DD;            // [B,H,T,DH] (pre-scaled, exp2 domain)
  u16* Ql    = Qh + MM * DD;
  u16* Kh    = Ql + MM * DD;             // [B,H,S,DH]
  u16* Kl    = Kh + NB * NH * SS * DHH;
  u16* Vt    = Kl + NB * NH * SS * DHH;  // [B,H,DH,S]
  u16* ao    = xh;                       // alias: x dead after gemm_qkv

  prep<<<dim3(PREP_TRANSW), 256, 0, stream>>>(x, wq, wk, wv, wo,
                                              xh, xl, wqkvh, wqkvl, wot);
  gemm_qkv<<<dim3(GQ_PASTV), 256, 0, stream>>>(xh, xl, wqkvh, wqkvl, pK, pV,
                                               Qh, Ql, Kh, Kl, Vt, dK, dV);
  attn<<<dim3(NB * NH * (TT / 128)), 256, 0, stream>>>(Qh, Ql, Kh, Kl, Vt, ao);
  gemm_out<<<dim3(32, 10), 256, 0, stream>>>(ao, wot, out);
}